// Round 6
// baseline (241.930 us; speedup 1.0000x reference)
//
#include <hip/hip_runtime.h>
#include <hip/hip_bf16.h>

// Problem constants
constexpr int NPAT = 8192;     // B*PH*PW = 8*32*32

typedef __attribute__((ext_vector_type(8))) short short8v;   // 8 bf16
typedef __attribute__((ext_vector_type(4))) float f32x4;

#define GLOAD16(g, l) __builtin_amdgcn_global_load_lds( \
    (const __attribute__((address_space(1))) void*)(g), \
    (__attribute__((address_space(3))) void*)(l), 16, 0, 0)

__device__ inline short bf16s(float f) {
    __hip_bfloat16 h = __float2bfloat16(f);
    return *reinterpret_cast<short*>(&h);
}
__device__ inline unsigned short bf16u(float f) {
    __hip_bfloat16 h = __float2bfloat16(f);
    return *reinterpret_cast<unsigned short*>(&h);
}
__device__ inline float bf2f(short s) {
    return __uint_as_float(((unsigned int)(unsigned short)s) << 16);
}

// ---------------------------------------------------------------------------
// K1: unfold x [8,64,128,128] -> proc bf16 [8192,16,64]
__global__ __launch_bounds__(256) void k_extract(const float* __restrict__ x,
                                                 __hip_bfloat16* __restrict__ proc) {
    __shared__ float tile[64][129];
    int t = threadIdx.x;
    int b = blockIdx.x >> 7, h = blockIdx.x & 127;
    for (int it = 0; it < 8; ++it) {
        int idx = it * 256 + t;
        int c = idx >> 5, w4 = (idx & 31) * 4;
        float4 v = *(const float4*)&x[(((size_t)b * 64 + c) * 128 + h) * 128 + w4];
        tile[c][w4] = v.x; tile[c][w4 + 1] = v.y;
        tile[c][w4 + 2] = v.z; tile[c][w4 + 3] = v.w;
    }
    __syncthreads();
    int ny = (h >> 2) * 32, py = h & 3;
    for (int it = 0; it < 16; ++it) {
        int pw = it * 8 + (t >> 5);          // pixel 0..127
        int cc = (t & 31) * 2;
        int n = (b << 10) + ny + (pw >> 2);
        int p = (py << 2) + (pw & 3);
        unsigned int u = (unsigned int)bf16u(tile[cc][pw]) |
                         ((unsigned int)bf16u(tile[cc + 1][pw]) << 16);
        *(unsigned int*)((__hip_bfloat16*)proc + ((size_t)n << 10) + (p << 6) + cc) = u;
    }
}

// ---------------------------------------------------------------------------
// K2: summary[n, c] = mean_p(pixel_positions) + MLP(coords)  -> bf16
__global__ __launch_bounds__(64) void k_summary(const float* __restrict__ pixpos,
                                                const float* __restrict__ w1,
                                                const float* __restrict__ b1,
                                                const float* __restrict__ w2,
                                                const float* __restrict__ b2,
                                                __hip_bfloat16* __restrict__ summary) {
    __shared__ float h[256];
    int n = blockIdx.x, t = threadIdx.x;  // 64 threads
    int rem = n & 1023;
    float cy = (float)(rem >> 5) * (1.f / 31.f);
    float cx = (float)(rem & 31) * (1.f / 31.f);
    for (int k = t; k < 256; k += 64) {
        float v = cy * w1[k] + cx * w1[256 + k] + b1[k];
        h[k] = v / (1.f + __expf(-v));   // silu
    }
    __syncthreads();
    float acc = b2[t];
    for (int k = 0; k < 256; ++k) acc += h[k] * w2[k * 64 + t];
    float pm = 0.f;
    for (int p = 0; p < 16; ++p) pm += pixpos[p * 64 + t];
    summary[n * 64 + t] = __float2bfloat16(acc + pm * (1.f / 16.f));
}

// ---------------------------------------------------------------------------
// K-prep-all: blocks 0..511: wn_w2 -> w2t [2][4096][256] bf16 (transposed)
//             blocks 512..575: conv_w -> cwt_g (pre-swizzled)
//             blocks 576..959: w1t / w2bt for k_mlp_mfma
__global__ __launch_bounds__(256) void k_prep_all(const float* __restrict__ w2,
                                                  const float* __restrict__ cw,
                                                  const float* __restrict__ wn_w1,
                                                  const float* __restrict__ bn_w1,
                                                  const float* __restrict__ bn_w2,
                                                  __hip_bfloat16* __restrict__ w2t,
                                                  __hip_bfloat16* __restrict__ cwt_g,
                                                  __hip_bfloat16* __restrict__ w1t,
                                                  __hip_bfloat16* __restrict__ w2bt) {
    __shared__ float tile[64][65];
    int bid = blockIdx.x;
    int t = threadIdx.x;
    if (bid < 512) {
        int b = bid >> 8;
        int rem = bid & 255;
        int kt = rem >> 6;
        int nt = rem & 63;
        const float* src = w2 + (size_t)b * 256 * 4096 + (size_t)(kt * 64) * 4096 + nt * 64;
        for (int it = 0; it < 16; ++it) {
            int idx = t + it * 256;
            int r = idx >> 6, c = idx & 63;
            tile[r][c] = src[(size_t)r * 4096 + c];
        }
        __syncthreads();
        __hip_bfloat16* dst = w2t + (size_t)b * 4096 * 256 + (size_t)(nt * 64) * 256 + kt * 64;
        for (int it = 0; it < 16; ++it) {
            int idx = t + it * 256;
            int rr = idx >> 6, cc = idx & 63;
            dst[rr * 256 + cc] = __float2bfloat16(tile[cc][rr]);
        }
    } else if (bid < 576) {
        int idx = (bid - 512) * 256 + t;   // 0..16383
        int oc = idx >> 6, cc = idx & 63;
        float v = cw[cc * 256 + oc];
        int el = oc * 64 + (((cc >> 3) ^ (oc & 7)) << 3) + (cc & 7);
        cwt_g[el] = __float2bfloat16(v);
    } else {
        int idx = (bid - 576) * 256 + t;   // 0..98303
        if (idx < 2 * 512 * 64) {
            int b = idx >> 15; int r = idx & 32767; int n = r >> 6; int k = r & 63;
            const float* src = (n < 256) ? wn_w1 : bn_w1;
            float v = src[((size_t)b * 64 + k) * 256 + (n & 255)];
            w1t[idx] = __float2bfloat16(v);
        } else {
            int j = idx - 2 * 512 * 64;
            int b = j >> 14; int r = j & 16383; int c = r >> 8; int k = r & 255;
            float v = bn_w2[((size_t)b * 256 + k) * 64 + c];
            w2bt[j] = __float2bfloat16(v);
        }
    }
}

// ---------------------------------------------------------------------------
// K3 (MFMA): both hyper-blocks at once. Per block: 32 patches.
__global__ __launch_bounds__(256) void k_mlp_mfma(const __hip_bfloat16* __restrict__ summary,
                                                  const __hip_bfloat16* __restrict__ w1t_all,
                                                  const float* __restrict__ wn_b1,
                                                  const float* __restrict__ bn_b1,
                                                  const __hip_bfloat16* __restrict__ w2bt_all,
                                                  const float* __restrict__ bn_b2,
                                                  __hip_bfloat16* __restrict__ h1_all,
                                                  float* __restrict__ bias_all) {
    __shared__ short st[32 * 64];
    __shared__ short hb[32 * 256];
    int t = threadIdx.x;
    int l = t & 63, w = t >> 6;
    int bi = blockIdx.x;
    int i = bi >> 8;
    int m0 = (bi & 255) * 32;
    int lrow = l & 15, hi = l >> 4;

    const __hip_bfloat16* w1t = w1t_all + (size_t)i * 512 * 64;
    const __hip_bfloat16* w2bt = w2bt_all + (size_t)i * 64 * 256;
    const float* b1w = wn_b1 + i * 256;
    const float* b1b = bn_b1 + i * 256;
    const float* b2b = bn_b2 + i * 64;
    __hip_bfloat16* h1out = h1_all + (size_t)i * NPAT * 256;
    float* biasout = bias_all + (size_t)i * NPAT * 64;

    {
        int chunk = w * 64 + l;
        int m = chunk >> 3, q = chunk & 7;
        int gq = q ^ (m & 7);
        GLOAD16((const char*)(summary + ((size_t)(m0 + m) << 6) + (gq << 3)),
                (char*)st + (size_t)(w * 64) * 16);
    }
    __syncthreads();

    f32x4 acc[8][2] = {};
    for (int ks = 0; ks < 2; ++ks) {
        short8v a[8], bb[2];
        for (int ii = 0; ii < 8; ++ii) {
            int n = w * 128 + ii * 16 + lrow;
            a[ii] = *(const short8v*)&w1t[(size_t)n * 64 + ks * 32 + hi * 8];
        }
        for (int j = 0; j < 2; ++j) {
            int m = j * 16 + lrow;
            int kk = ks * 4 + hi;
            bb[j] = *(const short8v*)((const char*)st + m * 128 + ((kk ^ (m & 7)) << 4));
        }
        for (int ii = 0; ii < 8; ++ii)
            for (int j = 0; j < 2; ++j)
                acc[ii][j] = __builtin_amdgcn_mfma_f32_16x16x32_bf16(a[ii], bb[j], acc[ii][j], 0, 0, 0);
    }
    if (w < 2) {
        for (int ii = 0; ii < 8; ++ii) {
            int n0_ = w * 128 + ii * 16 + hi * 4;
            float4 bw = *(const float4*)&b1w[n0_];
            float bwa[4] = {bw.x, bw.y, bw.z, bw.w};
            for (int j = 0; j < 2; ++j) {
                union { unsigned short s[4]; unsigned long long u; } pk;
                for (int r = 0; r < 4; ++r) {
                    float z = acc[ii][j][r] + bwa[r];
                    pk.s[r] = bf16u(z / (1.f + __expf(-z)));
                }
                int m = m0 + j * 16 + lrow;
                *(unsigned long long*)&h1out[(size_t)m * 256 + n0_] = pk.u;
            }
        }
    } else {
        for (int ii = 0; ii < 8; ++ii) {
            int nb0 = (w - 2) * 128 + ii * 16 + hi * 4;
            float4 bw = *(const float4*)&b1b[nb0];
            float bwa[4] = {bw.x, bw.y, bw.z, bw.w};
            for (int j = 0; j < 2; ++j) {
                union { unsigned short s[4]; unsigned long long u; } pk;
                for (int r = 0; r < 4; ++r) {
                    float z = acc[ii][j][r] + bwa[r];
                    pk.s[r] = bf16u(z / (1.f + __expf(-z)));
                }
                int mloc = j * 16 + lrow;
                int qq = nb0 >> 3;
                *(unsigned long long*)((char*)hb + mloc * 512 +
                                       ((qq ^ (mloc & 7)) << 4) + ((nb0 & 7) << 1)) = pk.u;
            }
        }
    }
    __syncthreads();

    f32x4 acc2[2] = {};
    for (int ks = 0; ks < 8; ++ks) {
        short8v a2 = *(const short8v*)&w2bt[(size_t)(w * 16 + lrow) * 256 + ks * 32 + hi * 8];
        for (int j = 0; j < 2; ++j) {
            int ml = j * 16 + lrow;
            int kk = ks * 4 + hi;
            short8v b2f = *(const short8v*)((const char*)hb + ml * 512 + ((kk ^ (ml & 7)) << 4));
            acc2[j] = __builtin_amdgcn_mfma_f32_16x16x32_bf16(a2, b2f, acc2[j], 0, 0, 0);
        }
    }
    {
        int c0 = w * 16 + hi * 4;
        float4 bv = *(const float4*)&b2b[c0];
        for (int j = 0; j < 2; ++j) {
            int m = m0 + j * 16 + lrow;
            float4 o;
            o.x = acc2[j][0] + bv.x; o.y = acc2[j][1] + bv.y;
            o.z = acc2[j][2] + bv.z; o.w = acc2[j][3] + bv.w;
            *(float4*)&biasout[(size_t)m * 64 + c0] = o;
        }
    }
}

// ---------------------------------------------------------------------------
// K-FUSED: per block: 64 patches (g), one 8-channel i-chunk (ic).
//   Phase 1 (GEMM): wgt_chunk[64p][512n] = h1[p,:] @ w2t[ic*512+n,:] + b2  (LDS, bf16)
//   Phase 2 (bmm):  per patch: nm = LN(src) in-register; D[i,tok] = wgt@nm^T;
//                   dst[tok, ic*8+i] = D + bias + src   (ping-pong dst)
// 512 threads = 8 waves. Wave w: GEMM n-range [w*64, w*64+64), bmm patches [w*8, w*8+8).
__global__ __launch_bounds__(512) void k_fused(const __hip_bfloat16* __restrict__ src,
                                               __hip_bfloat16* __restrict__ dst,
                                               const __hip_bfloat16* __restrict__ h1,
                                               const __hip_bfloat16* __restrict__ w2t,
                                               const float* __restrict__ b2,
                                               const float* __restrict__ bias,
                                               const float* __restrict__ ln_g,
                                               const float* __restrict__ ln_b) {
    __shared__ short Bb[2][512 * 32];        // w2t k-slab dbuf (src-preswizzled)
    __shared__ short Hb[2][64 * 32];         // h1 k-slab dbuf (src-preswizzled)
    __shared__ short wgt_l[64 * 512 + 512];  // wgt chunk + OOB pad

    int t = threadIdx.x;
    int l = t & 63, w = t >> 6;
    int ic = blockIdx.x & 7;                 // i-chunk -> XCD affinity
    int g = blockIdx.x >> 3;
    int n0 = g << 6;
    int lrow = l & 15, hi = l >> 4;

    // ---------------- prologue staging (k-slab 0)
    {
        const __hip_bfloat16* wsrc = w2t + (size_t)(ic * 512) * 256;
        for (int it = 0; it < 4; ++it) {
            int c = it * 512 + t;
            int row = c >> 2, q = c & 3;
            GLOAD16((const char*)(wsrc + (size_t)row * 256 + ((q ^ (row & 3)) << 3)),
                    (char*)Bb[0] + ((size_t)(it * 512 + w * 64) << 4));
        }
        if (w < 4) {
            int row = t >> 2, q = t & 3;
            GLOAD16((const char*)(h1 + (size_t)(n0 + row) * 256 + ((q ^ (row & 3)) << 3)),
                    (char*)Hb[0] + ((size_t)(w * 64) << 4));
        }
    }
    __syncthreads();

    // ---------------- GEMM: 8 k-steps of 32, 2-phase dbuf
    f32x4 acc[4][4] = {};    // [m-frag][n-frag]
    #pragma unroll
    for (int ks = 0; ks < 8; ++ks) {
        if (ks < 7) {
            int buf = (ks + 1) & 1;
            const __hip_bfloat16* wsrc = w2t + (size_t)(ic * 512) * 256 + (ks + 1) * 32;
            for (int it = 0; it < 4; ++it) {
                int c = it * 512 + t;
                int row = c >> 2, q = c & 3;
                GLOAD16((const char*)(wsrc + (size_t)row * 256 + ((q ^ (row & 3)) << 3)),
                        (char*)Bb[buf] + ((size_t)(it * 512 + w * 64) << 4));
            }
            if (w < 4) {
                int row = t >> 2, q = t & 3;
                GLOAD16((const char*)(h1 + (size_t)(n0 + row) * 256 + (ks + 1) * 32 + ((q ^ (row & 3)) << 3)),
                        (char*)Hb[buf] + ((size_t)(w * 64) << 4));
            }
        }
        int cur = ks & 1;
        short8v a[4], b[4];
        #pragma unroll
        for (int nf = 0; nf < 4; ++nf) {
            int row = w * 64 + nf * 16 + lrow;
            a[nf] = *(const short8v*)((const char*)Bb[cur] + row * 64 + ((hi ^ (row & 3)) << 4));
        }
        #pragma unroll
        for (int mf = 0; mf < 4; ++mf) {
            int row = mf * 16 + lrow;
            b[mf] = *(const short8v*)((const char*)Hb[cur] + row * 64 + ((hi ^ (row & 3)) << 4));
        }
        #pragma unroll
        for (int mf = 0; mf < 4; ++mf)
            #pragma unroll
            for (int nf = 0; nf < 4; ++nf)
                acc[mf][nf] = __builtin_amdgcn_mfma_f32_16x16x32_bf16(a[nf], b[mf], acc[mf][nf], 0, 0, 0);
        __syncthreads();
    }

    // ---------------- prefetch this wave's src rows for bmm (overlaps C-write)
    short8v ps0[8], ps1[8];
    #pragma unroll
    for (int pp = 0; pp < 8; ++pp) {
        const __hip_bfloat16* srow = src + ((size_t)(n0 + w * 8 + pp) << 10) + (lrow << 6);
        ps0[pp] = *(const short8v*)(srow + hi * 8);
        ps1[pp] = *(const short8v*)(srow + 32 + hi * 8);
    }

    // ---------------- C-write: acc -> wgt_l (bf16, XOR-swizzled), + wn_b2 bias
    {
        const float* b2c = b2 + ic * 512;
        #pragma unroll
        for (int mf = 0; mf < 4; ++mf) {
            int p = mf * 16 + lrow;
            int psw = p & 7;
            #pragma unroll
            for (int nf = 0; nf < 4; ++nf) {
                int nl = w * 64 + nf * 16 + hi * 4;
                float4 bv = *(const float4*)&b2c[nl];
                int i = nl >> 6, jq = (nl >> 3) & 7, e = nl & 7;
                union { unsigned short s[4]; unsigned long long u; } pk;
                pk.s[0] = bf16u(acc[mf][nf][0] + bv.x);
                pk.s[1] = bf16u(acc[mf][nf][1] + bv.y);
                pk.s[2] = bf16u(acc[mf][nf][2] + bv.z);
                pk.s[3] = bf16u(acc[mf][nf][3] + bv.w);
                *(unsigned long long*)((char*)wgt_l + p * 1024 + i * 128 +
                                       ((jq ^ i ^ psw) << 4) + e * 2) = pk.u;
            }
        }
    }
    __syncthreads();

    // ---------------- bmm: per patch, in-register LN + 2 MFMA + epilogue
    float4 ga = *(const float4*)&ln_g[hi * 8];
    float4 gb = *(const float4*)&ln_g[hi * 8 + 4];
    float4 gc = *(const float4*)&ln_g[32 + hi * 8];
    float4 gd = *(const float4*)&ln_g[32 + hi * 8 + 4];
    float4 ba = *(const float4*)&ln_b[hi * 8];
    float4 bb2 = *(const float4*)&ln_b[hi * 8 + 4];
    float4 bc = *(const float4*)&ln_b[32 + hi * 8];
    float4 bd = *(const float4*)&ln_b[32 + hi * 8 + 4];
    float gv[16] = {ga.x, ga.y, ga.z, ga.w, gb.x, gb.y, gb.z, gb.w,
                    gc.x, gc.y, gc.z, gc.w, gd.x, gd.y, gd.z, gd.w};
    float bv_[16] = {ba.x, ba.y, ba.z, ba.w, bb2.x, bb2.y, bb2.z, bb2.w,
                     bc.x, bc.y, bc.z, bc.w, bd.x, bd.y, bd.z, bd.w};

    #pragma unroll
    for (int pp = 0; pp < 8; ++pp) {
        int p = w * 8 + pp;
        float v0[8], v1[8];
        float sum = 0.f, sq = 0.f;
        #pragma unroll
        for (int e = 0; e < 8; ++e) {
            v0[e] = bf2f(ps0[pp][e]); v1[e] = bf2f(ps1[pp][e]);
            sum += v0[e] + v1[e];
            sq += v0[e] * v0[e] + v1[e] * v1[e];
        }
        sum += __shfl_xor(sum, 16); sq += __shfl_xor(sq, 16);
        sum += __shfl_xor(sum, 32); sq += __shfl_xor(sq, 32);
        float mean = sum * (1.f / 64.f);
        float var = sq * (1.f / 64.f) - mean * mean;
        float rinv = rsqrtf(var + 1e-5f);
        short8v nf0, nf1;
        #pragma unroll
        for (int e = 0; e < 8; ++e) {
            nf0[e] = bf16s((v0[e] - mean) * rinv * gv[e] + bv_[e]);
            nf1[e] = bf16s((v1[e] - mean) * rinv * gv[8 + e] + bv_[8 + e]);
        }
        int ir = l & 7;
        int swz = ir ^ pp;       // p&7 == pp
        const char* wl = (const char*)wgt_l + p * 1024 + ir * 128;
        short8v a0 = *(const short8v*)(wl + ((hi ^ swz) << 4));
        short8v a1 = *(const short8v*)(wl + (((hi + 4) ^ swz) << 4));
        f32x4 d = {};
        d = __builtin_amdgcn_mfma_f32_16x16x32_bf16(a0, nf0, d, 0, 0, 0);
        d = __builtin_amdgcn_mfma_f32_16x16x32_bf16(a1, nf1, d, 0, 0, 0);
        if (hi < 2) {
            int cbase = ic * 8 + hi * 4;
            size_t off = ((size_t)(n0 + p) << 10) + (lrow << 6) + cbase;
            unsigned long long rr = *(const unsigned long long*)(src + off);
            float4 bsv = *(const float4*)&bias[((size_t)(n0 + p) << 6) + cbase];
            float bav[4] = {bsv.x, bsv.y, bsv.z, bsv.w};
            union { unsigned short s[4]; unsigned long long u; } stp;
            #pragma unroll
            for (int r = 0; r < 4; ++r) {
                float res = bf2f((short)((rr >> (16 * r)) & 0xffff));
                stp.s[r] = bf16u(d[r] + bav[r] + res);
            }
            *(unsigned long long*)(dst + off) = stp.u;
        }
    }
}

// ---------------------------------------------------------------------------
// K6: 1x1 conv (64->256) + pixel shuffle, MFMA; proc is bf16.
__global__ __launch_bounds__(256) void k_conv_mfma(const __hip_bfloat16* __restrict__ proc,
                                                   const __hip_bfloat16* __restrict__ cwt_g,
                                                   const float* __restrict__ cb,
                                                   float* __restrict__ out) {
    __shared__ short cwt[256 * 64];
    __shared__ short msb[128 * 64];
    __shared__ float cbl[256];
    int t = threadIdx.x;
    int l = t & 63, wv = t >> 6;
    int b = blockIdx.x >> 7, hh = blockIdx.x & 127;

    for (int it = 0; it < 8; ++it) {
        int cid0 = it * 256 + wv * 64;
        GLOAD16((const char*)cwt_g + ((size_t)(cid0 + l) << 4),
                (char*)cwt + ((size_t)cid0 << 4));
    }
    cbl[t] = cb[t];
    int ny = (hh >> 2) * 32, py = hh & 3;
    for (int it = 0; it < 4; ++it) {
        int chunk = it * 256 + wv * 64 + l;
        int w = chunk >> 3, q = chunk & 7;
        int n = (b << 10) + ny + (w >> 2);
        int p = (py << 2) + (w & 3);
        int gq = q ^ (w & 7);
        GLOAD16((const char*)proc + (((size_t)n << 10) + (p << 6) + (gq << 3)) * 2,
                (char*)msb + (size_t)(it * 256 + wv * 64) * 16);
    }
    __syncthreads();

    int wvo = wv >> 1, wvw = wv & 1;
    int lrow = l & 15, lhi = l >> 4;
    f32x4 acc[8][4] = {};
    for (int ks = 0; ks < 2; ++ks) {
        int q = ks * 4 + lhi;
        short8v a[8], bb[4];
        for (int i = 0; i < 8; ++i) {
            int ocr = wvo * 128 + i * 16 + lrow;
            a[i] = *(const short8v*)((const char*)cwt + ocr * 128 + ((q ^ (ocr & 7)) << 4));
        }
        for (int j = 0; j < 4; ++j) {
            int wr = wvw * 64 + j * 16 + lrow;
            bb[j] = *(const short8v*)((const char*)msb + wr * 128 + ((q ^ (wr & 7)) << 4));
        }
        for (int i = 0; i < 8; ++i)
            for (int j = 0; j < 4; ++j)
                acc[i][j] = __builtin_amdgcn_mfma_f32_16x16x32_bf16(a[i], bb[j], acc[i][j], 0, 0, 0);
    }

    for (int i = 0; i < 8; ++i) {
        int oc4 = wvo * 128 + i * 16 + lhi * 4;
        int c = oc4 >> 2;
        float cb0 = cbl[oc4], cb1 = cbl[oc4 + 1], cb2 = cbl[oc4 + 2], cb3 = cbl[oc4 + 3];
        float* row0 = out + (((size_t)b * 64 + c) * 256 + 2 * hh) * 256;
        float* row1 = row0 + 256;
        for (int j = 0; j < 4; ++j) {
            int w = wvw * 64 + j * 16 + lrow;
            ((float2*)row0)[w] = make_float2(acc[i][j][0] + cb0, acc[i][j][1] + cb1);
            ((float2*)row1)[w] = make_float2(acc[i][j][2] + cb2, acc[i][j][3] + cb3);
        }
    }
}

// ---------------------------------------------------------------------------
extern "C" void kernel_launch(void* const* d_in, const int* in_sizes, int n_in,
                              void* d_out, int out_size, void* d_ws, size_t ws_size,
                              hipStream_t stream) {
    const float* x      = (const float*)d_in[0];
    const float* pixpos = (const float*)d_in[1];
    const float* ppe_w1 = (const float*)d_in[2];
    const float* ppe_b1 = (const float*)d_in[3];
    const float* ppe_w2 = (const float*)d_in[4];
    const float* ppe_b2 = (const float*)d_in[5];
    const float* ln_g   = (const float*)d_in[6];
    const float* ln_b   = (const float*)d_in[7];
    const float* wn_w1  = (const float*)d_in[8];
    const float* wn_b1  = (const float*)d_in[9];
    const float* wn_w2  = (const float*)d_in[10];
    const float* wn_b2  = (const float*)d_in[11];
    const float* bn_w1  = (const float*)d_in[12];
    const float* bn_b1  = (const float*)d_in[13];
    const float* bn_w2  = (const float*)d_in[14];
    const float* bn_b2  = (const float*)d_in[15];
    const float* conv_w = (const float*)d_in[16];
    const float* conv_b = (const float*)d_in[17];
    float* out = (float*)d_out;

    char* wsb = (char*)d_ws;
    __hip_bfloat16* procA = (__hip_bfloat16*)wsb; wsb += (size_t)NPAT * 1024 * 2;     // 16 MB
    __hip_bfloat16* procB = (__hip_bfloat16*)wsb; wsb += (size_t)NPAT * 1024 * 2;     // 16 MB
    __hip_bfloat16* h1    = (__hip_bfloat16*)wsb; wsb += (size_t)2 * NPAT * 256 * 2;  //  8 MB
    __hip_bfloat16* w2t   = (__hip_bfloat16*)wsb; wsb += (size_t)2 * 4096 * 256 * 2;  //  4 MB
    float* bias           = (float*)wsb;          wsb += (size_t)2 * NPAT * 64 * 4;   //  4 MB
    __hip_bfloat16* summ  = (__hip_bfloat16*)wsb; wsb += (size_t)NPAT * 64 * 2;       //  1 MB
    __hip_bfloat16* w1t   = (__hip_bfloat16*)wsb; wsb += (size_t)2 * 512 * 64 * 2;    // 128 KB
    __hip_bfloat16* w2bt  = (__hip_bfloat16*)wsb; wsb += (size_t)2 * 64 * 256 * 2;    //  64 KB
    __hip_bfloat16* cwt_g = (__hip_bfloat16*)wsb;                                     //  32 KB

    k_extract<<<1024, 256, 0, stream>>>(x, procA);
    k_summary<<<NPAT, 64, 0, stream>>>(pixpos, ppe_w1, ppe_b1, ppe_w2, ppe_b2, summ);
    k_prep_all<<<960, 256, 0, stream>>>(wn_w2, conv_w, wn_w1, bn_w1, bn_w2,
                                        w2t, cwt_g, w1t, w2bt);
    k_mlp_mfma<<<512, 256, 0, stream>>>(summ, w1t, wn_b1, bn_b1, w2bt, bn_b2, h1, bias);
    // hyper-block 0: procA -> procB ; hyper-block 1: procB -> procA
    k_fused<<<1024, 512, 0, stream>>>(procA, procB, h1, w2t, wn_b2, bias,
                                      ln_g, ln_b);
    k_fused<<<1024, 512, 0, stream>>>(procB, procA, h1 + (size_t)NPAT * 256,
                                      w2t + (size_t)4096 * 256, wn_b2 + 4096,
                                      bias + (size_t)NPAT * 64, ln_g + 64, ln_b + 64);
    k_conv_mfma<<<1024, 256, 0, stream>>>(procA, cwt_g, conv_b, out);
}

// Round 7
// 173.402 us; speedup vs baseline: 1.3952x; 1.3952x over previous
//
#include <hip/hip_runtime.h>
#include <hip/hip_bf16.h>

// Problem constants
constexpr int NPAT = 8192;     // B*PH*PW = 8*32*32

typedef __attribute__((ext_vector_type(8))) short short8v;   // 8 bf16
typedef __attribute__((ext_vector_type(4))) float f32x4;

#define GLOAD16(g, l) __builtin_amdgcn_global_load_lds( \
    (const __attribute__((address_space(1))) void*)(g), \
    (__attribute__((address_space(3))) void*)(l), 16, 0, 0)

__device__ inline short bf16s(float f) {
    __hip_bfloat16 h = __float2bfloat16(f);
    return *reinterpret_cast<short*>(&h);
}
__device__ inline unsigned short bf16u(float f) {
    __hip_bfloat16 h = __float2bfloat16(f);
    return *reinterpret_cast<unsigned short*>(&h);
}
__device__ inline float bf2f(short s) {
    return __uint_as_float(((unsigned int)(unsigned short)s) << 16);
}

// ---------------------------------------------------------------------------
// K1: unfold x [8,64,128,128] -> proc bf16 [8192,16,64]
__global__ __launch_bounds__(256) void k_extract(const float* __restrict__ x,
                                                 __hip_bfloat16* __restrict__ proc) {
    __shared__ float tile[64][129];
    int t = threadIdx.x;
    int b = blockIdx.x >> 7, h = blockIdx.x & 127;
    for (int it = 0; it < 8; ++it) {
        int idx = it * 256 + t;
        int c = idx >> 5, w4 = (idx & 31) * 4;
        float4 v = *(const float4*)&x[(((size_t)b * 64 + c) * 128 + h) * 128 + w4];
        tile[c][w4] = v.x; tile[c][w4 + 1] = v.y;
        tile[c][w4 + 2] = v.z; tile[c][w4 + 3] = v.w;
    }
    __syncthreads();
    int ny = (h >> 2) * 32, py = h & 3;
    for (int it = 0; it < 16; ++it) {
        int pw = it * 8 + (t >> 5);          // pixel 0..127
        int cc = (t & 31) * 2;
        int n = (b << 10) + ny + (pw >> 2);
        int p = (py << 2) + (pw & 3);
        unsigned int u = (unsigned int)bf16u(tile[cc][pw]) |
                         ((unsigned int)bf16u(tile[cc + 1][pw]) << 16);
        *(unsigned int*)((__hip_bfloat16*)proc + ((size_t)n << 10) + (p << 6) + cc) = u;
    }
}

// ---------------------------------------------------------------------------
// K2: summary[n, c] = mean_p(pixel_positions) + MLP(coords)  -> bf16
__global__ __launch_bounds__(64) void k_summary(const float* __restrict__ pixpos,
                                                const float* __restrict__ w1,
                                                const float* __restrict__ b1,
                                                const float* __restrict__ w2,
                                                const float* __restrict__ b2,
                                                __hip_bfloat16* __restrict__ summary) {
    __shared__ float h[256];
    int n = blockIdx.x, t = threadIdx.x;  // 64 threads
    int rem = n & 1023;
    float cy = (float)(rem >> 5) * (1.f / 31.f);
    float cx = (float)(rem & 31) * (1.f / 31.f);
    for (int k = t; k < 256; k += 64) {
        float v = cy * w1[k] + cx * w1[256 + k] + b1[k];
        h[k] = v / (1.f + __expf(-v));   // silu
    }
    __syncthreads();
    float acc = b2[t];
    for (int k = 0; k < 256; ++k) acc += h[k] * w2[k * 64 + t];
    float pm = 0.f;
    for (int p = 0; p < 16; ++p) pm += pixpos[p * 64 + t];
    summary[n * 64 + t] = __float2bfloat16(acc + pm * (1.f / 16.f));
}

// ---------------------------------------------------------------------------
// K-prep-all: blocks 0..511: wn_w2 -> w2t [2][4096][256] bf16 (transposed)
//             blocks 512..575: conv_w -> cwt_g (pre-swizzled)
//             blocks 576..959: w1t / w2bt for k_mlp_mfma
__global__ __launch_bounds__(256) void k_prep_all(const float* __restrict__ w2,
                                                  const float* __restrict__ cw,
                                                  const float* __restrict__ wn_w1,
                                                  const float* __restrict__ bn_w1,
                                                  const float* __restrict__ bn_w2,
                                                  __hip_bfloat16* __restrict__ w2t,
                                                  __hip_bfloat16* __restrict__ cwt_g,
                                                  __hip_bfloat16* __restrict__ w1t,
                                                  __hip_bfloat16* __restrict__ w2bt) {
    __shared__ float tile[64][65];
    int bid = blockIdx.x;
    int t = threadIdx.x;
    if (bid < 512) {
        int b = bid >> 8;
        int rem = bid & 255;
        int kt = rem >> 6;
        int nt = rem & 63;
        const float* src = w2 + (size_t)b * 256 * 4096 + (size_t)(kt * 64) * 4096 + nt * 64;
        for (int it = 0; it < 16; ++it) {
            int idx = t + it * 256;
            int r = idx >> 6, c = idx & 63;
            tile[r][c] = src[(size_t)r * 4096 + c];
        }
        __syncthreads();
        __hip_bfloat16* dst = w2t + (size_t)b * 4096 * 256 + (size_t)(nt * 64) * 256 + kt * 64;
        for (int it = 0; it < 16; ++it) {
            int idx = t + it * 256;
            int rr = idx >> 6, cc = idx & 63;
            dst[rr * 256 + cc] = __float2bfloat16(tile[cc][rr]);
        }
    } else if (bid < 576) {
        int idx = (bid - 512) * 256 + t;   // 0..16383
        int oc = idx >> 6, cc = idx & 63;
        float v = cw[cc * 256 + oc];
        int el = oc * 64 + (((cc >> 3) ^ (oc & 7)) << 3) + (cc & 7);
        cwt_g[el] = __float2bfloat16(v);
    } else {
        int idx = (bid - 576) * 256 + t;   // 0..98303
        if (idx < 2 * 512 * 64) {
            int b = idx >> 15; int r = idx & 32767; int n = r >> 6; int k = r & 63;
            const float* src = (n < 256) ? wn_w1 : bn_w1;
            float v = src[((size_t)b * 64 + k) * 256 + (n & 255)];
            w1t[idx] = __float2bfloat16(v);
        } else {
            int j = idx - 2 * 512 * 64;
            int b = j >> 14; int r = j & 16383; int c = r >> 8; int k = r & 255;
            float v = bn_w2[((size_t)b * 256 + k) * 64 + c];
            w2bt[j] = __float2bfloat16(v);
        }
    }
}

// ---------------------------------------------------------------------------
// K3 (MFMA): both hyper-blocks at once. Per block: 32 patches.
__global__ __launch_bounds__(256) void k_mlp_mfma(const __hip_bfloat16* __restrict__ summary,
                                                  const __hip_bfloat16* __restrict__ w1t_all,
                                                  const float* __restrict__ wn_b1,
                                                  const float* __restrict__ bn_b1,
                                                  const __hip_bfloat16* __restrict__ w2bt_all,
                                                  const float* __restrict__ bn_b2,
                                                  __hip_bfloat16* __restrict__ h1_all,
                                                  float* __restrict__ bias_all) {
    __shared__ short st[32 * 64];
    __shared__ short hb[32 * 256];
    int t = threadIdx.x;
    int l = t & 63, w = t >> 6;
    int bi = blockIdx.x;
    int i = bi >> 8;
    int m0 = (bi & 255) * 32;
    int lrow = l & 15, hi = l >> 4;

    const __hip_bfloat16* w1t = w1t_all + (size_t)i * 512 * 64;
    const __hip_bfloat16* w2bt = w2bt_all + (size_t)i * 64 * 256;
    const float* b1w = wn_b1 + i * 256;
    const float* b1b = bn_b1 + i * 256;
    const float* b2b = bn_b2 + i * 64;
    __hip_bfloat16* h1out = h1_all + (size_t)i * NPAT * 256;
    float* biasout = bias_all + (size_t)i * NPAT * 64;

    {
        int chunk = w * 64 + l;
        int m = chunk >> 3, q = chunk & 7;
        int gq = q ^ (m & 7);
        GLOAD16((const char*)(summary + ((size_t)(m0 + m) << 6) + (gq << 3)),
                (char*)st + (size_t)(w * 64) * 16);
    }
    __syncthreads();

    f32x4 acc[8][2] = {};
    for (int ks = 0; ks < 2; ++ks) {
        short8v a[8], bb[2];
        for (int ii = 0; ii < 8; ++ii) {
            int n = w * 128 + ii * 16 + lrow;
            a[ii] = *(const short8v*)&w1t[(size_t)n * 64 + ks * 32 + hi * 8];
        }
        for (int j = 0; j < 2; ++j) {
            int m = j * 16 + lrow;
            int kk = ks * 4 + hi;
            bb[j] = *(const short8v*)((const char*)st + m * 128 + ((kk ^ (m & 7)) << 4));
        }
        for (int ii = 0; ii < 8; ++ii)
            for (int j = 0; j < 2; ++j)
                acc[ii][j] = __builtin_amdgcn_mfma_f32_16x16x32_bf16(a[ii], bb[j], acc[ii][j], 0, 0, 0);
    }
    if (w < 2) {
        for (int ii = 0; ii < 8; ++ii) {
            int n0_ = w * 128 + ii * 16 + hi * 4;
            float4 bw = *(const float4*)&b1w[n0_];
            float bwa[4] = {bw.x, bw.y, bw.z, bw.w};
            for (int j = 0; j < 2; ++j) {
                union { unsigned short s[4]; unsigned long long u; } pk;
                for (int r = 0; r < 4; ++r) {
                    float z = acc[ii][j][r] + bwa[r];
                    pk.s[r] = bf16u(z / (1.f + __expf(-z)));
                }
                int m = m0 + j * 16 + lrow;
                *(unsigned long long*)&h1out[(size_t)m * 256 + n0_] = pk.u;
            }
        }
    } else {
        for (int ii = 0; ii < 8; ++ii) {
            int nb0 = (w - 2) * 128 + ii * 16 + hi * 4;
            float4 bw = *(const float4*)&b1b[nb0];
            float bwa[4] = {bw.x, bw.y, bw.z, bw.w};
            for (int j = 0; j < 2; ++j) {
                union { unsigned short s[4]; unsigned long long u; } pk;
                for (int r = 0; r < 4; ++r) {
                    float z = acc[ii][j][r] + bwa[r];
                    pk.s[r] = bf16u(z / (1.f + __expf(-z)));
                }
                int mloc = j * 16 + lrow;
                int qq = nb0 >> 3;
                *(unsigned long long*)((char*)hb + mloc * 512 +
                                       ((qq ^ (mloc & 7)) << 4) + ((nb0 & 7) << 1)) = pk.u;
            }
        }
    }
    __syncthreads();

    f32x4 acc2[2] = {};
    for (int ks = 0; ks < 8; ++ks) {
        short8v a2 = *(const short8v*)&w2bt[(size_t)(w * 16 + lrow) * 256 + ks * 32 + hi * 8];
        for (int j = 0; j < 2; ++j) {
            int ml = j * 16 + lrow;
            int kk = ks * 4 + hi;
            short8v b2f = *(const short8v*)((const char*)hb + ml * 512 + ((kk ^ (ml & 7)) << 4));
            acc2[j] = __builtin_amdgcn_mfma_f32_16x16x32_bf16(a2, b2f, acc2[j], 0, 0, 0);
        }
    }
    {
        int c0 = w * 16 + hi * 4;
        float4 bv = *(const float4*)&b2b[c0];
        for (int j = 0; j < 2; ++j) {
            int m = m0 + j * 16 + lrow;
            float4 o;
            o.x = acc2[j][0] + bv.x; o.y = acc2[j][1] + bv.y;
            o.z = acc2[j][2] + bv.z; o.w = acc2[j][3] + bv.w;
            *(float4*)&biasout[(size_t)m * 64 + c0] = o;
        }
    }
}

// ---------------------------------------------------------------------------
// K4: MFMA GEMM. wgt[m,n] = h1[m,:256] @ w2t[n,:256] + b2[n], bf16 out.
// 128x128 tile, BK=64 (4 k-iters), XOR-swizzled LDS (pre-swizzled global src),
// coalesced epilogue through padded LDS (full 256B row stores).
__global__ __launch_bounds__(256) void k_wgt_mfma(const __hip_bfloat16* __restrict__ h1,
                                                  const __hip_bfloat16* __restrict__ w2t,
                                                  const float* __restrict__ b2,
                                                  __hip_bfloat16* __restrict__ wgt) {
    __shared__ short sm[2][128 * 68];   // staging: [0]=A(h1) [1]=B(w2t), 16KB each used
                                        // epilogue overlay: 128 rows x 136 shorts
    int t = threadIdx.x;
    int l = t & 63, w = t >> 6;
    int mt = blockIdx.x & 63, nt = blockIdx.x >> 6;
    int m0 = mt << 7, n0 = nt << 7;
    int wr = w >> 1, wc = w & 1;
    int lrow = l & 15, hi = l >> 4;

    f32x4 acc[4][4] = {};   // [n-frag][m-frag]

    const char* gA = (const char*)(h1 + (size_t)m0 * 256);
    const char* gB = (const char*)(w2t + (size_t)n0 * 256);

    for (int ks = 0; ks < 4; ++ks) {
        int k0 = ks * 64;
        // stage A,B 128x64 tiles: 1024 chunks of 16B each, 4/thread/tile.
        // source k-chunk pre-XOR-swizzled by (row&7); LDS dst linear.
        #pragma unroll
        for (int it = 0; it < 4; ++it) {
            int c = it * 256 + t;
            int row = c >> 3, q = c & 7;
            size_t goff = ((size_t)row * 256 + k0 + ((q ^ (row & 7)) << 3)) * 2;
            char* ldst = (char*)0 + (size_t)(it * 256 + w * 64) * 16;
            GLOAD16(gA + goff, (char*)sm[0] + (size_t)ldst);
            GLOAD16(gB + goff, (char*)sm[1] + (size_t)ldst);
        }
        __syncthreads();
        #pragma unroll
        for (int kk = 0; kk < 2; ++kk) {
            int kq = kk * 4 + hi;
            short8v a[4], b[4];
            #pragma unroll
            for (int fi = 0; fi < 4; ++fi) {
                int row = wc * 64 + fi * 16 + lrow;
                a[fi] = *(const short8v*)((const char*)sm[1] + row * 128 + ((kq ^ (row & 7)) << 4));
            }
            #pragma unroll
            for (int fj = 0; fj < 4; ++fj) {
                int row = wr * 64 + fj * 16 + lrow;
                b[fj] = *(const short8v*)((const char*)sm[0] + row * 128 + ((kq ^ (row & 7)) << 4));
            }
            #pragma unroll
            for (int fi = 0; fi < 4; ++fi)
                #pragma unroll
                for (int fj = 0; fj < 4; ++fj)
                    acc[fi][fj] = __builtin_amdgcn_mfma_f32_16x16x32_bf16(a[fi], b[fj], acc[fi][fj], 0, 0, 0);
        }
        __syncthreads();
    }

    // epilogue: acc -> LDS (bf16, +bias), then coalesced row stores
    short* epi = (short*)sm;   // stride 136 shorts (272B): low-conflict
    #pragma unroll
    for (int fi = 0; fi < 4; ++fi) {
        int nl = wc * 64 + fi * 16 + hi * 4;
        float4 bv = *(const float4*)&b2[n0 + nl];
        float bva[4] = {bv.x, bv.y, bv.z, bv.w};
        #pragma unroll
        for (int fj = 0; fj < 4; ++fj) {
            int m = wr * 64 + fj * 16 + lrow;
            union { unsigned short s[4]; unsigned long long u; } pk;
            #pragma unroll
            for (int r = 0; r < 4; ++r)
                pk.s[r] = bf16u(acc[fi][fj][r] + bva[r]);
            *(unsigned long long*)((char*)epi + (size_t)m * 272 + nl * 2) = pk.u;
        }
    }
    __syncthreads();
    #pragma unroll
    for (int pass = 0; pass < 8; ++pass) {
        int row = pass * 16 + (t >> 4);
        int c8 = (t & 15) * 8;
        uint4 v = *(const uint4*)((const char*)epi + (size_t)row * 272 + c8 * 2);
        *(uint4*)&wgt[(size_t)(m0 + row) * 4096 + n0 + c8] = v;
    }
}

// ---------------------------------------------------------------------------
// K5 (MFMA): per patch (one wave): nm = LN(proc); proc += wgt @ nm^T + bias.
__global__ __launch_bounds__(256) void k_bmm(__hip_bfloat16* __restrict__ proc,
                                             const __hip_bfloat16* __restrict__ wgt,
                                             const float* __restrict__ bias,
                                             const float* __restrict__ ln_g,
                                             const float* __restrict__ ln_b) {
    __shared__ short nm_lds[4][16][72];
    int t = threadIdx.x;
    int w = t >> 6, l = t & 63;
    int n = blockIdx.x * 4 + w;
    int p = l & 15, hi = l >> 4;

    const __hip_bfloat16* prow = proc + ((size_t)n << 10) + (p << 6) + (hi << 4);
    short8v r0 = *(const short8v*)prow;
    short8v r1 = *(const short8v*)(prow + 8);
    float pr[16];
    for (int i = 0; i < 8; ++i) { pr[i] = bf2f(r0[i]); pr[8 + i] = bf2f(r1[i]); }

    float s = 0.f, s2 = 0.f;
    for (int i = 0; i < 16; ++i) { s += pr[i]; s2 += pr[i] * pr[i]; }
    s += __shfl_xor(s, 16);  s2 += __shfl_xor(s2, 16);
    s += __shfl_xor(s, 32);  s2 += __shfl_xor(s2, 32);
    float mean = s * (1.f / 64.f);
    float var = s2 * (1.f / 64.f) - mean * mean;
    float rinv = rsqrtf(var + 1e-5f);

    float gg[16], bb_[16];
    {
        const float* gp = ln_g + (hi << 4);
        const float* bp = ln_b + (hi << 4);
        *(float4*)(gg)      = *(const float4*)(gp);
        *(float4*)(gg + 4)  = *(const float4*)(gp + 4);
        *(float4*)(gg + 8)  = *(const float4*)(gp + 8);
        *(float4*)(gg + 12) = *(const float4*)(gp + 12);
        *(float4*)(bb_)      = *(const float4*)(bp);
        *(float4*)(bb_ + 4)  = *(const float4*)(bp + 4);
        *(float4*)(bb_ + 8)  = *(const float4*)(bp + 8);
        *(float4*)(bb_ + 12) = *(const float4*)(bp + 12);
    }
    short8v nm0, nm1;
    for (int i = 0; i < 8; ++i)
        nm0[i] = bf16s((pr[i] - mean) * rinv * gg[i] + bb_[i]);
    for (int i = 0; i < 8; ++i)
        nm1[i] = bf16s((pr[8 + i] - mean) * rinv * gg[8 + i] + bb_[8 + i]);
    *(short8v*)&nm_lds[w][p][hi * 16]     = nm0;
    *(short8v*)&nm_lds[w][p][hi * 16 + 8] = nm1;
    __syncthreads();

    const __hip_bfloat16* wrow = wgt + ((size_t)n << 12);
    short8v af[4][2];
    for (int ib = 0; ib < 4; ++ib)
        for (int ks = 0; ks < 2; ++ks)
            af[ib][ks] = *(const short8v*)&wrow[(ib * 16 + p) * 64 + ks * 32 + hi * 8];

    short8v bf0 = *(const short8v*)&nm_lds[w][p][hi * 8];
    short8v bf1 = *(const short8v*)&nm_lds[w][p][32 + hi * 8];

    f32x4 acc[4] = {};
    for (int ib = 0; ib < 4; ++ib) {
        acc[ib] = __builtin_amdgcn_mfma_f32_16x16x32_bf16(af[ib][0], bf0, acc[ib], 0, 0, 0);
        acc[ib] = __builtin_amdgcn_mfma_f32_16x16x32_bf16(af[ib][1], bf1, acc[ib], 0, 0, 0);
    }

    __hip_bfloat16* orow = proc + ((size_t)n << 10) + (p << 6);
    const float* brow = bias + ((size_t)n << 6);
    for (int ib = 0; ib < 4; ++ib) {
        int i0 = ib * 16 + hi * 4;
        unsigned long long rr = *(const unsigned long long*)&orow[i0];
        float4 bsv = *(const float4*)&brow[i0];
        float ba[4] = {bsv.x, bsv.y, bsv.z, bsv.w};
        union { unsigned short s[4]; unsigned long long u; } stp;
        for (int r = 0; r < 4; ++r) {
            float res = bf2f((short)((rr >> (16 * r)) & 0xffff));
            stp.s[r] = bf16u(acc[ib][r] + ba[r] + res);
        }
        *(unsigned long long*)&orow[i0] = stp.u;
    }
}

// ---------------------------------------------------------------------------
// K6: 1x1 conv (64->256) + pixel shuffle, MFMA; proc is bf16.
__global__ __launch_bounds__(256) void k_conv_mfma(const __hip_bfloat16* __restrict__ proc,
                                                   const __hip_bfloat16* __restrict__ cwt_g,
                                                   const float* __restrict__ cb,
                                                   float* __restrict__ out) {
    __shared__ short cwt[256 * 64];
    __shared__ short msb[128 * 64];
    __shared__ float cbl[256];
    int t = threadIdx.x;
    int l = t & 63, wv = t >> 6;
    int b = blockIdx.x >> 7, hh = blockIdx.x & 127;

    for (int it = 0; it < 8; ++it) {
        int cid0 = it * 256 + wv * 64;
        GLOAD16((const char*)cwt_g + ((size_t)(cid0 + l) << 4),
                (char*)cwt + ((size_t)cid0 << 4));
    }
    cbl[t] = cb[t];
    int ny = (hh >> 2) * 32, py = hh & 3;
    for (int it = 0; it < 4; ++it) {
        int chunk = it * 256 + wv * 64 + l;
        int w = chunk >> 3, q = chunk & 7;
        int n = (b << 10) + ny + (w >> 2);
        int p = (py << 2) + (w & 3);
        int gq = q ^ (w & 7);
        GLOAD16((const char*)proc + (((size_t)n << 10) + (p << 6) + (gq << 3)) * 2,
                (char*)msb + (size_t)(it * 256 + wv * 64) * 16);
    }
    __syncthreads();

    int wvo = wv >> 1, wvw = wv & 1;
    int lrow = l & 15, lhi = l >> 4;
    f32x4 acc[8][4] = {};
    for (int ks = 0; ks < 2; ++ks) {
        int q = ks * 4 + lhi;
        short8v a[8], bb[4];
        for (int i = 0; i < 8; ++i) {
            int ocr = wvo * 128 + i * 16 + lrow;
            a[i] = *(const short8v*)((const char*)cwt + ocr * 128 + ((q ^ (ocr & 7)) << 4));
        }
        for (int j = 0; j < 4; ++j) {
            int wr = wvw * 64 + j * 16 + lrow;
            bb[j] = *(const short8v*)((const char*)msb + wr * 128 + ((q ^ (wr & 7)) << 4));
        }
        for (int i = 0; i < 8; ++i)
            for (int j = 0; j < 4; ++j)
                acc[i][j] = __builtin_amdgcn_mfma_f32_16x16x32_bf16(a[i], bb[j], acc[i][j], 0, 0, 0);
    }

    for (int i = 0; i < 8; ++i) {
        int oc4 = wvo * 128 + i * 16 + lhi * 4;
        int c = oc4 >> 2;
        float cb0 = cbl[oc4], cb1 = cbl[oc4 + 1], cb2 = cbl[oc4 + 2], cb3 = cbl[oc4 + 3];
        float* row0 = out + (((size_t)b * 64 + c) * 256 + 2 * hh) * 256;
        float* row1 = row0 + 256;
        for (int j = 0; j < 4; ++j) {
            int w = wvw * 64 + j * 16 + lrow;
            ((float2*)row0)[w] = make_float2(acc[i][j][0] + cb0, acc[i][j][1] + cb1);
            ((float2*)row1)[w] = make_float2(acc[i][j][2] + cb2, acc[i][j][3] + cb3);
        }
    }
}

// ---------------------------------------------------------------------------
extern "C" void kernel_launch(void* const* d_in, const int* in_sizes, int n_in,
                              void* d_out, int out_size, void* d_ws, size_t ws_size,
                              hipStream_t stream) {
    const float* x      = (const float*)d_in[0];
    const float* pixpos = (const float*)d_in[1];
    const float* ppe_w1 = (const float*)d_in[2];
    const float* ppe_b1 = (const float*)d_in[3];
    const float* ppe_w2 = (const float*)d_in[4];
    const float* ppe_b2 = (const float*)d_in[5];
    const float* ln_g   = (const float*)d_in[6];
    const float* ln_b   = (const float*)d_in[7];
    const float* wn_w1  = (const float*)d_in[8];
    const float* wn_b1  = (const float*)d_in[9];
    const float* wn_w2  = (const float*)d_in[10];
    const float* wn_b2  = (const float*)d_in[11];
    const float* bn_w1  = (const float*)d_in[12];
    const float* bn_b1  = (const float*)d_in[13];
    const float* bn_w2  = (const float*)d_in[14];
    const float* bn_b2  = (const float*)d_in[15];
    const float* conv_w = (const float*)d_in[16];
    const float* conv_b = (const float*)d_in[17];
    float* out = (float*)d_out;

    char* wsb = (char*)d_ws;
    __hip_bfloat16* procb = (__hip_bfloat16*)wsb; wsb += (size_t)NPAT * 1024 * 2;     // 16 MB
    __hip_bfloat16* wgt   = (__hip_bfloat16*)wsb; wsb += (size_t)NPAT * 4096 * 2;     // 64 MB
    __hip_bfloat16* h1    = (__hip_bfloat16*)wsb; wsb += (size_t)2 * NPAT * 256 * 2;  //  8 MB
    __hip_bfloat16* w2t   = (__hip_bfloat16*)wsb; wsb += (size_t)2 * 4096 * 256 * 2;  //  4 MB
    float* bias           = (float*)wsb;          wsb += (size_t)2 * NPAT * 64 * 4;   //  4 MB
    __hip_bfloat16* summ  = (__hip_bfloat16*)wsb; wsb += (size_t)NPAT * 64 * 2;       //  1 MB
    __hip_bfloat16* w1t   = (__hip_bfloat16*)wsb; wsb += (size_t)2 * 512 * 64 * 2;    // 128 KB
    __hip_bfloat16* w2bt  = (__hip_bfloat16*)wsb; wsb += (size_t)2 * 64 * 256 * 2;    //  64 KB
    __hip_bfloat16* cwt_g = (__hip_bfloat16*)wsb;                                     //  32 KB

    k_extract<<<1024, 256, 0, stream>>>(x, procb);
    k_summary<<<NPAT, 64, 0, stream>>>(pixpos, ppe_w1, ppe_b1, ppe_w2, ppe_b2, summ);
    k_prep_all<<<960, 256, 0, stream>>>(wn_w2, conv_w, wn_w1, bn_w1, bn_w2,
                                        w2t, cwt_g, w1t, w2bt);
    k_mlp_mfma<<<512, 256, 0, stream>>>(summ, w1t, wn_b1, bn_b1, w2bt, bn_b2, h1, bias);
    for (int i = 0; i < 2; ++i) {
        k_wgt_mfma<<<2048, 256, 0, stream>>>(h1 + (size_t)i * NPAT * 256,
                                             w2t + (size_t)i * 4096 * 256,
                                             wn_b2 + (size_t)i * 4096, wgt);
        k_bmm<<<NPAT / 4, 256, 0, stream>>>(procb, wgt, bias + (size_t)i * NPAT * 64,
                                            ln_g + i * 64, ln_b + i * 64);
    }
    k_conv_mfma<<<1024, 256, 0, stream>>>(procb, cwt_g, conv_b, out);
}

// Round 8
// 167.023 us; speedup vs baseline: 1.4485x; 1.0382x over previous
//
#include <hip/hip_runtime.h>
#include <hip/hip_bf16.h>

// Problem constants
constexpr int NPAT = 8192;     // B*PH*PW = 8*32*32

typedef __attribute__((ext_vector_type(8))) short short8v;   // 8 bf16
typedef __attribute__((ext_vector_type(4))) float f32x4;

#define GLOAD16(g, l) __builtin_amdgcn_global_load_lds( \
    (const __attribute__((address_space(1))) void*)(g), \
    (__attribute__((address_space(3))) void*)(l), 16, 0, 0)

__device__ inline short bf16s(float f) {
    __hip_bfloat16 h = __float2bfloat16(f);
    return *reinterpret_cast<short*>(&h);
}
__device__ inline unsigned short bf16u(float f) {
    __hip_bfloat16 h = __float2bfloat16(f);
    return *reinterpret_cast<unsigned short*>(&h);
}
__device__ inline float bf2f(short s) {
    return __uint_as_float(((unsigned int)(unsigned short)s) << 16);
}

// ---------------------------------------------------------------------------
// K-SETUP: block-range dispatch.
//   [0,1024):    unfold x -> proc bf16
//   [1024,3072): summary (4 patches/block, wave-per-patch)
//   [3072,4032): weight prep (w2t transpose, cwt swizzle, w1t/w2bt)
__global__ __launch_bounds__(256) void k_setup(const float* __restrict__ x,
                                               __hip_bfloat16* __restrict__ proc,
                                               const float* __restrict__ pixpos,
                                               const float* __restrict__ pw1,
                                               const float* __restrict__ pb1,
                                               const float* __restrict__ pw2,
                                               const float* __restrict__ pb2,
                                               __hip_bfloat16* __restrict__ summ,
                                               const float* __restrict__ w2,
                                               const float* __restrict__ cw,
                                               const float* __restrict__ wn_w1,
                                               const float* __restrict__ bn_w1,
                                               const float* __restrict__ bn_w2,
                                               __hip_bfloat16* __restrict__ w2t,
                                               __hip_bfloat16* __restrict__ cwt_g,
                                               __hip_bfloat16* __restrict__ w1t,
                                               __hip_bfloat16* __restrict__ w2bt) {
    __shared__ __align__(16) char smem[33024];
    int bid = blockIdx.x;
    int t = threadIdx.x;
    if (bid < 1024) {
        // ---- extract
        float (*tile)[129] = (float(*)[129])smem;
        int b = bid >> 7, h = bid & 127;
        for (int it = 0; it < 8; ++it) {
            int idx = it * 256 + t;
            int c = idx >> 5, w4 = (idx & 31) * 4;
            float4 v = *(const float4*)&x[(((size_t)b * 64 + c) * 128 + h) * 128 + w4];
            tile[c][w4] = v.x; tile[c][w4 + 1] = v.y;
            tile[c][w4 + 2] = v.z; tile[c][w4 + 3] = v.w;
        }
        __syncthreads();
        int ny = (h >> 2) * 32, py = h & 3;
        for (int it = 0; it < 16; ++it) {
            int pw = it * 8 + (t >> 5);
            int cc = (t & 31) * 2;
            int n = (b << 10) + ny + (pw >> 2);
            int p = (py << 2) + (pw & 3);
            unsigned int u = (unsigned int)bf16u(tile[cc][pw]) |
                             ((unsigned int)bf16u(tile[cc + 1][pw]) << 16);
            *(unsigned int*)(proc + ((size_t)n << 10) + (p << 6) + cc) = u;
        }
    } else if (bid < 3072) {
        // ---- summary: wave w handles patch n
        float (*hs)[260] = (float(*)[260])smem;
        int l = t & 63, w = t >> 6;
        int n = (bid - 1024) * 4 + w;
        int rem = n & 1023;
        float cy = (float)(rem >> 5) * (1.f / 31.f);
        float cx = (float)(rem & 31) * (1.f / 31.f);
        for (int k4 = 0; k4 < 4; ++k4) {
            int k = k4 * 64 + l;
            float v = cy * pw1[k] + cx * pw1[256 + k] + pb1[k];
            hs[w][k] = v / (1.f + __expf(-v));
        }
        float acc = pb2[l];
        for (int k = 0; k < 256; ++k) acc += hs[w][k] * pw2[k * 64 + l];
        float pm = 0.f;
        for (int p = 0; p < 16; ++p) pm += pixpos[p * 64 + l];
        summ[(size_t)n * 64 + l] = __float2bfloat16(acc + pm * (1.f / 16.f));
    } else {
        int pb = bid - 3072;
        if (pb < 512) {
            float (*tile)[65] = (float(*)[65])smem;
            int b = pb >> 8;
            int rem = pb & 255;
            int kt = rem >> 6, nt = rem & 63;
            const float* src = w2 + (size_t)b * 256 * 4096 + (size_t)(kt * 64) * 4096 + nt * 64;
            for (int it = 0; it < 16; ++it) {
                int idx = t + it * 256;
                int r = idx >> 6, c = idx & 63;
                tile[r][c] = src[(size_t)r * 4096 + c];
            }
            __syncthreads();
            __hip_bfloat16* dst = w2t + (size_t)b * 4096 * 256 + (size_t)(nt * 64) * 256 + kt * 64;
            for (int it = 0; it < 16; ++it) {
                int idx = t + it * 256;
                int rr = idx >> 6, cc = idx & 63;
                dst[rr * 256 + cc] = __float2bfloat16(tile[cc][rr]);
            }
        } else if (pb < 576) {
            int idx = (pb - 512) * 256 + t;
            int oc = idx >> 6, cc = idx & 63;
            float v = cw[cc * 256 + oc];
            int el = oc * 64 + (((cc >> 3) ^ (oc & 7)) << 3) + (cc & 7);
            cwt_g[el] = __float2bfloat16(v);
        } else {
            int idx = (pb - 576) * 256 + t;
            if (idx < 2 * 512 * 64) {
                int b = idx >> 15; int r = idx & 32767; int n = r >> 6; int k = r & 63;
                const float* src = (n < 256) ? wn_w1 : bn_w1;
                float v = src[((size_t)b * 64 + k) * 256 + (n & 255)];
                w1t[idx] = __float2bfloat16(v);
            } else {
                int j = idx - 2 * 512 * 64;
                int b = j >> 14; int r = j & 16383; int c = r >> 8; int k = r & 255;
                float v = bn_w2[((size_t)b * 256 + k) * 64 + c];
                w2bt[j] = __float2bfloat16(v);
            }
        }
    }
}

// ---------------------------------------------------------------------------
// K3 (MFMA): both hyper-blocks at once. Per block: 32 patches.
__global__ __launch_bounds__(256) void k_mlp_mfma(const __hip_bfloat16* __restrict__ summary,
                                                  const __hip_bfloat16* __restrict__ w1t_all,
                                                  const float* __restrict__ wn_b1,
                                                  const float* __restrict__ bn_b1,
                                                  const __hip_bfloat16* __restrict__ w2bt_all,
                                                  const float* __restrict__ bn_b2,
                                                  __hip_bfloat16* __restrict__ h1_all,
                                                  float* __restrict__ bias_all) {
    __shared__ short st[32 * 64];
    __shared__ short hb[32 * 256];
    int t = threadIdx.x;
    int l = t & 63, w = t >> 6;
    int bi = blockIdx.x;
    int i = bi >> 8;
    int m0 = (bi & 255) * 32;
    int lrow = l & 15, hi = l >> 4;

    const __hip_bfloat16* w1t = w1t_all + (size_t)i * 512 * 64;
    const __hip_bfloat16* w2bt = w2bt_all + (size_t)i * 64 * 256;
    const float* b1w = wn_b1 + i * 256;
    const float* b1b = bn_b1 + i * 256;
    const float* b2b = bn_b2 + i * 64;
    __hip_bfloat16* h1out = h1_all + (size_t)i * NPAT * 256;
    float* biasout = bias_all + (size_t)i * NPAT * 64;

    {
        int chunk = w * 64 + l;
        int m = chunk >> 3, q = chunk & 7;
        int gq = q ^ (m & 7);
        GLOAD16((const char*)(summary + ((size_t)(m0 + m) << 6) + (gq << 3)),
                (char*)st + (size_t)(w * 64) * 16);
    }
    __syncthreads();

    f32x4 acc[8][2] = {};
    for (int ks = 0; ks < 2; ++ks) {
        short8v a[8], bb[2];
        for (int ii = 0; ii < 8; ++ii) {
            int n = w * 128 + ii * 16 + lrow;
            a[ii] = *(const short8v*)&w1t[(size_t)n * 64 + ks * 32 + hi * 8];
        }
        for (int j = 0; j < 2; ++j) {
            int m = j * 16 + lrow;
            int kk = ks * 4 + hi;
            bb[j] = *(const short8v*)((const char*)st + m * 128 + ((kk ^ (m & 7)) << 4));
        }
        for (int ii = 0; ii < 8; ++ii)
            for (int j = 0; j < 2; ++j)
                acc[ii][j] = __builtin_amdgcn_mfma_f32_16x16x32_bf16(a[ii], bb[j], acc[ii][j], 0, 0, 0);
    }
    if (w < 2) {
        for (int ii = 0; ii < 8; ++ii) {
            int n0_ = w * 128 + ii * 16 + hi * 4;
            float4 bw = *(const float4*)&b1w[n0_];
            float bwa[4] = {bw.x, bw.y, bw.z, bw.w};
            for (int j = 0; j < 2; ++j) {
                union { unsigned short s[4]; unsigned long long u; } pk;
                for (int r = 0; r < 4; ++r) {
                    float z = acc[ii][j][r] + bwa[r];
                    pk.s[r] = bf16u(z / (1.f + __expf(-z)));
                }
                int m = m0 + j * 16 + lrow;
                *(unsigned long long*)&h1out[(size_t)m * 256 + n0_] = pk.u;
            }
        }
    } else {
        for (int ii = 0; ii < 8; ++ii) {
            int nb0 = (w - 2) * 128 + ii * 16 + hi * 4;
            float4 bw = *(const float4*)&b1b[nb0];
            float bwa[4] = {bw.x, bw.y, bw.z, bw.w};
            for (int j = 0; j < 2; ++j) {
                union { unsigned short s[4]; unsigned long long u; } pk;
                for (int r = 0; r < 4; ++r) {
                    float z = acc[ii][j][r] + bwa[r];
                    pk.s[r] = bf16u(z / (1.f + __expf(-z)));
                }
                int mloc = j * 16 + lrow;
                int qq = nb0 >> 3;
                *(unsigned long long*)((char*)hb + mloc * 512 +
                                       ((qq ^ (mloc & 7)) << 4) + ((nb0 & 7) << 1)) = pk.u;
            }
        }
    }
    __syncthreads();

    f32x4 acc2[2] = {};
    for (int ks = 0; ks < 8; ++ks) {
        short8v a2 = *(const short8v*)&w2bt[(size_t)(w * 16 + lrow) * 256 + ks * 32 + hi * 8];
        for (int j = 0; j < 2; ++j) {
            int ml = j * 16 + lrow;
            int kk = ks * 4 + hi;
            short8v b2f = *(const short8v*)((const char*)hb + ml * 512 + ((kk ^ (ml & 7)) << 4));
            acc2[j] = __builtin_amdgcn_mfma_f32_16x16x32_bf16(a2, b2f, acc2[j], 0, 0, 0);
        }
    }
    {
        int c0 = w * 16 + hi * 4;
        float4 bv = *(const float4*)&b2b[c0];
        for (int j = 0; j < 2; ++j) {
            int m = m0 + j * 16 + lrow;
            float4 o;
            o.x = acc2[j][0] + bv.x; o.y = acc2[j][1] + bv.y;
            o.z = acc2[j][2] + bv.z; o.w = acc2[j][3] + bv.w;
            *(float4*)&biasout[(size_t)m * 64 + c0] = o;
        }
    }
}

// ---------------------------------------------------------------------------
// wgt GEMM body (128x128 tile, BK=64, both-sides swizzle, coalesced epilogue)
__device__ __forceinline__ void wgt_gemm_body(int bid,
                                              const __hip_bfloat16* __restrict__ h1,
                                              const __hip_bfloat16* __restrict__ w2t,
                                              const float* __restrict__ b2,
                                              __hip_bfloat16* __restrict__ wgt) {
    __shared__ short sm[2][128 * 68];
    int t = threadIdx.x;
    int l = t & 63, w = t >> 6;
    int mt = bid & 63, nt = bid >> 6;
    int m0 = mt << 7, n0 = nt << 7;
    int wr = w >> 1, wc = w & 1;
    int lrow = l & 15, hi = l >> 4;

    f32x4 acc[4][4] = {};

    const char* gA = (const char*)(h1 + (size_t)m0 * 256);
    const char* gB = (const char*)(w2t + (size_t)n0 * 256);

    for (int ks = 0; ks < 4; ++ks) {
        int k0 = ks * 64;
        #pragma unroll
        for (int it = 0; it < 4; ++it) {
            int c = it * 256 + t;
            int row = c >> 3, q = c & 7;
            size_t goff = ((size_t)row * 256 + k0 + ((q ^ (row & 7)) << 3)) * 2;
            size_t ldst = (size_t)(it * 256 + w * 64) * 16;
            GLOAD16(gA + goff, (char*)sm[0] + ldst);
            GLOAD16(gB + goff, (char*)sm[1] + ldst);
        }
        __syncthreads();
        #pragma unroll
        for (int kk = 0; kk < 2; ++kk) {
            int kq = kk * 4 + hi;
            short8v a[4], b[4];
            #pragma unroll
            for (int fi = 0; fi < 4; ++fi) {
                int row = wc * 64 + fi * 16 + lrow;
                a[fi] = *(const short8v*)((const char*)sm[1] + row * 128 + ((kq ^ (row & 7)) << 4));
            }
            #pragma unroll
            for (int fj = 0; fj < 4; ++fj) {
                int row = wr * 64 + fj * 16 + lrow;
                b[fj] = *(const short8v*)((const char*)sm[0] + row * 128 + ((kq ^ (row & 7)) << 4));
            }
            #pragma unroll
            for (int fi = 0; fi < 4; ++fi)
                #pragma unroll
                for (int fj = 0; fj < 4; ++fj)
                    acc[fi][fj] = __builtin_amdgcn_mfma_f32_16x16x32_bf16(a[fi], b[fj], acc[fi][fj], 0, 0, 0);
        }
        __syncthreads();
    }

    short* epi = (short*)sm;
    #pragma unroll
    for (int fi = 0; fi < 4; ++fi) {
        int nl = wc * 64 + fi * 16 + hi * 4;
        float4 bv = *(const float4*)&b2[n0 + nl];
        float bva[4] = {bv.x, bv.y, bv.z, bv.w};
        #pragma unroll
        for (int fj = 0; fj < 4; ++fj) {
            int m = wr * 64 + fj * 16 + lrow;
            union { unsigned short s[4]; unsigned long long u; } pk;
            #pragma unroll
            for (int r = 0; r < 4; ++r)
                pk.s[r] = bf16u(acc[fi][fj][r] + bva[r]);
            *(unsigned long long*)((char*)epi + (size_t)m * 272 + nl * 2) = pk.u;
        }
    }
    __syncthreads();
    #pragma unroll
    for (int pass = 0; pass < 8; ++pass) {
        int row = pass * 16 + (t >> 4);
        int c8 = (t & 15) * 8;
        uint4 v = *(const uint4*)((const char*)epi + (size_t)row * 272 + c8 * 2);
        *(uint4*)&wgt[(size_t)(m0 + row) * 4096 + n0 + c8] = v;
    }
}

// ---------------------------------------------------------------------------
// bmm body: per patch (one wave): nm = LN(proc); proc += wgt @ nm^T + bias.
__device__ __forceinline__ void bmm_body(int bid,
                                         __hip_bfloat16* __restrict__ proc,
                                         const __hip_bfloat16* __restrict__ wgt,
                                         const float* __restrict__ bias,
                                         const float* __restrict__ ln_g,
                                         const float* __restrict__ ln_b) {
    __shared__ short nm_lds[4][16][72];
    int t = threadIdx.x;
    int w = t >> 6, l = t & 63;
    int n = bid * 4 + w;
    int p = l & 15, hi = l >> 4;

    const __hip_bfloat16* prow = proc + ((size_t)n << 10) + (p << 6) + (hi << 4);
    short8v r0 = *(const short8v*)prow;
    short8v r1 = *(const short8v*)(prow + 8);
    float pr[16];
    for (int i = 0; i < 8; ++i) { pr[i] = bf2f(r0[i]); pr[8 + i] = bf2f(r1[i]); }

    float s = 0.f, s2 = 0.f;
    for (int i = 0; i < 16; ++i) { s += pr[i]; s2 += pr[i] * pr[i]; }
    s += __shfl_xor(s, 16);  s2 += __shfl_xor(s2, 16);
    s += __shfl_xor(s, 32);  s2 += __shfl_xor(s2, 32);
    float mean = s * (1.f / 64.f);
    float var = s2 * (1.f / 64.f) - mean * mean;
    float rinv = rsqrtf(var + 1e-5f);

    float gg[16], bb_[16];
    {
        const float* gp = ln_g + (hi << 4);
        const float* bp = ln_b + (hi << 4);
        *(float4*)(gg)      = *(const float4*)(gp);
        *(float4*)(gg + 4)  = *(const float4*)(gp + 4);
        *(float4*)(gg + 8)  = *(const float4*)(gp + 8);
        *(float4*)(gg + 12) = *(const float4*)(gp + 12);
        *(float4*)(bb_)      = *(const float4*)(bp);
        *(float4*)(bb_ + 4)  = *(const float4*)(bp + 4);
        *(float4*)(bb_ + 8)  = *(const float4*)(bp + 8);
        *(float4*)(bb_ + 12) = *(const float4*)(bp + 12);
    }
    short8v nm0, nm1;
    for (int i = 0; i < 8; ++i)
        nm0[i] = bf16s((pr[i] - mean) * rinv * gg[i] + bb_[i]);
    for (int i = 0; i < 8; ++i)
        nm1[i] = bf16s((pr[8 + i] - mean) * rinv * gg[8 + i] + bb_[8 + i]);
    *(short8v*)&nm_lds[w][p][hi * 16]     = nm0;
    *(short8v*)&nm_lds[w][p][hi * 16 + 8] = nm1;
    __syncthreads();

    const __hip_bfloat16* wrow = wgt + ((size_t)n << 12);
    short8v af[4][2];
    for (int ib = 0; ib < 4; ++ib)
        for (int ks = 0; ks < 2; ++ks)
            af[ib][ks] = *(const short8v*)&wrow[(ib * 16 + p) * 64 + ks * 32 + hi * 8];

    short8v bf0 = *(const short8v*)&nm_lds[w][p][hi * 8];
    short8v bf1 = *(const short8v*)&nm_lds[w][p][32 + hi * 8];

    f32x4 acc[4] = {};
    for (int ib = 0; ib < 4; ++ib) {
        acc[ib] = __builtin_amdgcn_mfma_f32_16x16x32_bf16(af[ib][0], bf0, acc[ib], 0, 0, 0);
        acc[ib] = __builtin_amdgcn_mfma_f32_16x16x32_bf16(af[ib][1], bf1, acc[ib], 0, 0, 0);
    }

    __hip_bfloat16* orow = proc + ((size_t)n << 10) + (p << 6);
    const float* brow = bias + ((size_t)n << 6);
    for (int ib = 0; ib < 4; ++ib) {
        int i0 = ib * 16 + hi * 4;
        unsigned long long rr = *(const unsigned long long*)&orow[i0];
        float4 bsv = *(const float4*)&brow[i0];
        float ba[4] = {bsv.x, bsv.y, bsv.z, bsv.w};
        union { unsigned short s[4]; unsigned long long u; } stp;
        for (int r = 0; r < 4; ++r) {
            float res = bf2f((short)((rr >> (16 * r)) & 0xffff));
            stp.s[r] = bf16u(acc[ib][r] + ba[r] + res);
        }
        *(unsigned long long*)&orow[i0] = stp.u;
    }
}

// ---------------------------------------------------------------------------
__global__ __launch_bounds__(256) void k_wgt_mfma(const __hip_bfloat16* __restrict__ h1,
                                                  const __hip_bfloat16* __restrict__ w2t,
                                                  const float* __restrict__ b2,
                                                  __hip_bfloat16* __restrict__ wgt) {
    wgt_gemm_body(blockIdx.x, h1, w2t, b2, wgt);
}

// K-COMBO: blocks 0..2047 compute wgt for hyper-block 1 (into wgt1 scratch in
// d_out); blocks 2048..4095 run bmm for hyper-block 0 (compute ∥ memory).
__global__ __launch_bounds__(256) void k_combo(const __hip_bfloat16* __restrict__ h1b,
                                               const __hip_bfloat16* __restrict__ w2tb,
                                               const float* __restrict__ b2b,
                                               __hip_bfloat16* __restrict__ wgt1,
                                               __hip_bfloat16* __restrict__ proc,
                                               const __hip_bfloat16* __restrict__ wgt0,
                                               const float* __restrict__ bias0,
                                               const float* __restrict__ ln_g,
                                               const float* __restrict__ ln_b) {
    if (blockIdx.x < 2048)
        wgt_gemm_body(blockIdx.x, h1b, w2tb, b2b, wgt1);
    else
        bmm_body(blockIdx.x - 2048, proc, wgt0, bias0, ln_g, ln_b);
}

__global__ __launch_bounds__(256) void k_bmm(__hip_bfloat16* __restrict__ proc,
                                             const __hip_bfloat16* __restrict__ wgt,
                                             const float* __restrict__ bias,
                                             const float* __restrict__ ln_g,
                                             const float* __restrict__ ln_b) {
    bmm_body(blockIdx.x, proc, wgt, bias, ln_g, ln_b);
}

// ---------------------------------------------------------------------------
// K6: 1x1 conv (64->256) + pixel shuffle, MFMA; proc is bf16.
__global__ __launch_bounds__(256) void k_conv_mfma(const __hip_bfloat16* __restrict__ proc,
                                                   const __hip_bfloat16* __restrict__ cwt_g,
                                                   const float* __restrict__ cb,
                                                   float* __restrict__ out) {
    __shared__ short cwt[256 * 64];
    __shared__ short msb[128 * 64];
    __shared__ float cbl[256];
    int t = threadIdx.x;
    int l = t & 63, wv = t >> 6;
    int b = blockIdx.x >> 7, hh = blockIdx.x & 127;

    for (int it = 0; it < 8; ++it) {
        int cid0 = it * 256 + wv * 64;
        GLOAD16((const char*)cwt_g + ((size_t)(cid0 + l) << 4),
                (char*)cwt + ((size_t)cid0 << 4));
    }
    cbl[t] = cb[t];
    int ny = (hh >> 2) * 32, py = hh & 3;
    for (int it = 0; it < 4; ++it) {
        int chunk = it * 256 + wv * 64 + l;
        int w = chunk >> 3, q = chunk & 7;
        int n = (b << 10) + ny + (w >> 2);
        int p = (py << 2) + (w & 3);
        int gq = q ^ (w & 7);
        GLOAD16((const char*)proc + (((size_t)n << 10) + (p << 6) + (gq << 3)) * 2,
                (char*)msb + (size_t)(it * 256 + wv * 64) * 16);
    }
    __syncthreads();

    int wvo = wv >> 1, wvw = wv & 1;
    int lrow = l & 15, lhi = l >> 4;
    f32x4 acc[8][4] = {};
    for (int ks = 0; ks < 2; ++ks) {
        int q = ks * 4 + lhi;
        short8v a[8], bb[4];
        for (int i = 0; i < 8; ++i) {
            int ocr = wvo * 128 + i * 16 + lrow;
            a[i] = *(const short8v*)((const char*)cwt + ocr * 128 + ((q ^ (ocr & 7)) << 4));
        }
        for (int j = 0; j < 4; ++j) {
            int wr = wvw * 64 + j * 16 + lrow;
            bb[j] = *(const short8v*)((const char*)msb + wr * 128 + ((q ^ (wr & 7)) << 4));
        }
        for (int i = 0; i < 8; ++i)
            for (int j = 0; j < 4; ++j)
                acc[i][j] = __builtin_amdgcn_mfma_f32_16x16x32_bf16(a[i], bb[j], acc[i][j], 0, 0, 0);
    }

    for (int i = 0; i < 8; ++i) {
        int oc4 = wvo * 128 + i * 16 + lhi * 4;
        int c = oc4 >> 2;
        float cb0 = cbl[oc4], cb1 = cbl[oc4 + 1], cb2 = cbl[oc4 + 2], cb3 = cbl[oc4 + 3];
        float* row0 = out + (((size_t)b * 64 + c) * 256 + 2 * hh) * 256;
        float* row1 = row0 + 256;
        for (int j = 0; j < 4; ++j) {
            int w = wvw * 64 + j * 16 + lrow;
            ((float2*)row0)[w] = make_float2(acc[i][j][0] + cb0, acc[i][j][1] + cb1);
            ((float2*)row1)[w] = make_float2(acc[i][j][2] + cb2, acc[i][j][3] + cb3);
        }
    }
}

// ---------------------------------------------------------------------------
extern "C" void kernel_launch(void* const* d_in, const int* in_sizes, int n_in,
                              void* d_out, int out_size, void* d_ws, size_t ws_size,
                              hipStream_t stream) {
    const float* x      = (const float*)d_in[0];
    const float* pixpos = (const float*)d_in[1];
    const float* ppe_w1 = (const float*)d_in[2];
    const float* ppe_b1 = (const float*)d_in[3];
    const float* ppe_w2 = (const float*)d_in[4];
    const float* ppe_b2 = (const float*)d_in[5];
    const float* ln_g   = (const float*)d_in[6];
    const float* ln_b   = (const float*)d_in[7];
    const float* wn_w1  = (const float*)d_in[8];
    const float* wn_b1  = (const float*)d_in[9];
    const float* wn_w2  = (const float*)d_in[10];
    const float* wn_b2  = (const float*)d_in[11];
    const float* bn_w1  = (const float*)d_in[12];
    const float* bn_b1  = (const float*)d_in[13];
    const float* bn_w2  = (const float*)d_in[14];
    const float* bn_b2  = (const float*)d_in[15];
    const float* conv_w = (const float*)d_in[16];
    const float* conv_b = (const float*)d_in[17];
    float* out = (float*)d_out;

    char* wsb = (char*)d_ws;
    __hip_bfloat16* procb = (__hip_bfloat16*)wsb; wsb += (size_t)NPAT * 1024 * 2;     // 16 MB
    __hip_bfloat16* wgt0  = (__hip_bfloat16*)wsb; wsb += (size_t)NPAT * 4096 * 2;     // 64 MB
    __hip_bfloat16* h1    = (__hip_bfloat16*)wsb; wsb += (size_t)2 * NPAT * 256 * 2;  //  8 MB
    __hip_bfloat16* w2t   = (__hip_bfloat16*)wsb; wsb += (size_t)2 * 4096 * 256 * 2;  //  4 MB
    float* bias           = (float*)wsb;          wsb += (size_t)2 * NPAT * 64 * 4;   //  4 MB
    __hip_bfloat16* summ  = (__hip_bfloat16*)wsb; wsb += (size_t)NPAT * 64 * 2;       //  1 MB
    __hip_bfloat16* w1t   = (__hip_bfloat16*)wsb; wsb += (size_t)2 * 512 * 64 * 2;    // 128 KB
    __hip_bfloat16* w2bt  = (__hip_bfloat16*)wsb; wsb += (size_t)2 * 64 * 256 * 2;    //  64 KB
    __hip_bfloat16* cwt_g = (__hip_bfloat16*)wsb;                                     //  32 KB
    // wgt for hyper-block 1 lives in d_out scratch (first 64 MB of 134 MB);
    // fully rewritten before k_conv's final output overwrite.
    __hip_bfloat16* wgt1  = (__hip_bfloat16*)d_out;

    k_setup<<<4032, 256, 0, stream>>>(x, procb, pixpos, ppe_w1, ppe_b1, ppe_w2, ppe_b2,
                                      summ, wn_w2, conv_w, wn_w1, bn_w1, bn_w2,
                                      w2t, cwt_g, w1t, w2bt);
    k_mlp_mfma<<<512, 256, 0, stream>>>(summ, w1t, wn_b1, bn_b1, w2bt, bn_b2, h1, bias);
    k_wgt_mfma<<<2048, 256, 0, stream>>>(h1, w2t, wn_b2, wgt0);
    k_combo<<<4096, 256, 0, stream>>>(h1 + (size_t)NPAT * 256, w2t + (size_t)4096 * 256,
                                      wn_b2 + 4096, wgt1,
                                      procb, wgt0, bias, ln_g, ln_b);
    k_bmm<<<2048, 256, 0, stream>>>(procb, wgt1, bias + (size_t)NPAT * 64,
                                    ln_g + 64, ln_b + 64);
    k_conv_mfma<<<1024, 256, 0, stream>>>(procb, cwt_g, conv_b, out);
}

// Round 9
// 89.509 us; speedup vs baseline: 2.7029x; 1.8660x over previous
//
#include <hip/hip_runtime.h>
#include <hip/hip_bf16.h>

// Problem constants
constexpr int NPAT = 8192;     // B*PH*PW = 8*32*32
constexpr int NPER = 1024;     // coords period: summary/h1/bias/wgt repeat every 1024

typedef __attribute__((ext_vector_type(8))) short short8v;   // 8 bf16
typedef __attribute__((ext_vector_type(4))) float f32x4;

#define GLOAD16(g, l) __builtin_amdgcn_global_load_lds( \
    (const __attribute__((address_space(1))) void*)(g), \
    (__attribute__((address_space(3))) void*)(l), 16, 0, 0)

__device__ inline short bf16s(float f) {
    __hip_bfloat16 h = __float2bfloat16(f);
    return *reinterpret_cast<short*>(&h);
}
__device__ inline unsigned short bf16u(float f) {
    __hip_bfloat16 h = __float2bfloat16(f);
    return *reinterpret_cast<unsigned short*>(&h);
}
__device__ inline float bf2f(short s) {
    return __uint_as_float(((unsigned int)(unsigned short)s) << 16);
}

// ---------------------------------------------------------------------------
// K-SETUP: block-range dispatch.
//   [0,1024):    unfold x -> proc bf16
//   [1024,1280): summary for 1024 distinct coords (4 patches/block)
//   [1280,2240): weight prep (w2t transpose, cwt swizzle, w1t/w2bt)
__global__ __launch_bounds__(256) void k_setup(const float* __restrict__ x,
                                               __hip_bfloat16* __restrict__ proc,
                                               const float* __restrict__ pixpos,
                                               const float* __restrict__ pw1,
                                               const float* __restrict__ pb1,
                                               const float* __restrict__ pw2,
                                               const float* __restrict__ pb2,
                                               __hip_bfloat16* __restrict__ summ,
                                               const float* __restrict__ w2,
                                               const float* __restrict__ cw,
                                               const float* __restrict__ wn_w1,
                                               const float* __restrict__ bn_w1,
                                               const float* __restrict__ bn_w2,
                                               __hip_bfloat16* __restrict__ w2t,
                                               __hip_bfloat16* __restrict__ cwt_g,
                                               __hip_bfloat16* __restrict__ w1t,
                                               __hip_bfloat16* __restrict__ w2bt) {
    __shared__ __align__(16) char smem[33024];
    int bid = blockIdx.x;
    int t = threadIdx.x;
    if (bid < 1024) {
        // ---- extract
        float (*tile)[129] = (float(*)[129])smem;
        int b = bid >> 7, h = bid & 127;
        for (int it = 0; it < 8; ++it) {
            int idx = it * 256 + t;
            int c = idx >> 5, w4 = (idx & 31) * 4;
            float4 v = *(const float4*)&x[(((size_t)b * 64 + c) * 128 + h) * 128 + w4];
            tile[c][w4] = v.x; tile[c][w4 + 1] = v.y;
            tile[c][w4 + 2] = v.z; tile[c][w4 + 3] = v.w;
        }
        __syncthreads();
        int ny = (h >> 2) * 32, py = h & 3;
        for (int it = 0; it < 16; ++it) {
            int pw = it * 8 + (t >> 5);
            int cc = (t & 31) * 2;
            int n = (b << 10) + ny + (pw >> 2);
            int p = (py << 2) + (pw & 3);
            unsigned int u = (unsigned int)bf16u(tile[cc][pw]) |
                             ((unsigned int)bf16u(tile[cc + 1][pw]) << 16);
            *(unsigned int*)(proc + ((size_t)n << 10) + (p << 6) + cc) = u;
        }
    } else if (bid < 1280) {
        // ---- summary: wave w handles distinct-coord patch n in [0,1024)
        float (*hs)[260] = (float(*)[260])smem;
        int l = t & 63, w = t >> 6;
        int n = (bid - 1024) * 4 + w;
        float cy = (float)(n >> 5) * (1.f / 31.f);
        float cx = (float)(n & 31) * (1.f / 31.f);
        for (int k4 = 0; k4 < 4; ++k4) {
            int k = k4 * 64 + l;
            float v = cy * pw1[k] + cx * pw1[256 + k] + pb1[k];
            hs[w][k] = v / (1.f + __expf(-v));
        }
        float acc = pb2[l];
        for (int k = 0; k < 256; ++k) acc += hs[w][k] * pw2[k * 64 + l];
        float pm = 0.f;
        for (int p = 0; p < 16; ++p) pm += pixpos[p * 64 + l];
        summ[(size_t)n * 64 + l] = __float2bfloat16(acc + pm * (1.f / 16.f));
    } else {
        int pb = bid - 1280;
        if (pb < 512) {
            float (*tile)[65] = (float(*)[65])smem;
            int b = pb >> 8;
            int rem = pb & 255;
            int kt = rem >> 6, nt = rem & 63;
            const float* src = w2 + (size_t)b * 256 * 4096 + (size_t)(kt * 64) * 4096 + nt * 64;
            for (int it = 0; it < 16; ++it) {
                int idx = t + it * 256;
                int r = idx >> 6, c = idx & 63;
                tile[r][c] = src[(size_t)r * 4096 + c];
            }
            __syncthreads();
            __hip_bfloat16* dst = w2t + (size_t)b * 4096 * 256 + (size_t)(nt * 64) * 256 + kt * 64;
            for (int it = 0; it < 16; ++it) {
                int idx = t + it * 256;
                int rr = idx >> 6, cc = idx & 63;
                dst[rr * 256 + cc] = __float2bfloat16(tile[cc][rr]);
            }
        } else if (pb < 576) {
            int idx = (pb - 512) * 256 + t;
            int oc = idx >> 6, cc = idx & 63;
            float v = cw[cc * 256 + oc];
            int el = oc * 64 + (((cc >> 3) ^ (oc & 7)) << 3) + (cc & 7);
            cwt_g[el] = __float2bfloat16(v);
        } else {
            int idx = (pb - 576) * 256 + t;
            if (idx < 2 * 512 * 64) {
                int b = idx >> 15; int r = idx & 32767; int n = r >> 6; int k = r & 63;
                const float* src = (n < 256) ? wn_w1 : bn_w1;
                float v = src[((size_t)b * 64 + k) * 256 + (n & 255)];
                w1t[idx] = __float2bfloat16(v);
            } else {
                int j = idx - 2 * 512 * 64;
                int b = j >> 14; int r = j & 16383; int c = r >> 8; int k = r & 255;
                float v = bn_w2[((size_t)b * 256 + k) * 64 + c];
                w2bt[j] = __float2bfloat16(v);
            }
        }
    }
}

// ---------------------------------------------------------------------------
// K3 (MFMA): both hyper-blocks, 1024 distinct patches. 64 blocks, 32 patches each.
__global__ __launch_bounds__(256) void k_mlp_mfma(const __hip_bfloat16* __restrict__ summary,
                                                  const __hip_bfloat16* __restrict__ w1t_all,
                                                  const float* __restrict__ wn_b1,
                                                  const float* __restrict__ bn_b1,
                                                  const __hip_bfloat16* __restrict__ w2bt_all,
                                                  const float* __restrict__ bn_b2,
                                                  __hip_bfloat16* __restrict__ h1_all,
                                                  float* __restrict__ bias_all) {
    __shared__ short st[32 * 64];
    __shared__ short hb[32 * 256];
    int t = threadIdx.x;
    int l = t & 63, w = t >> 6;
    int bi = blockIdx.x;
    int i = bi >> 5;
    int m0 = (bi & 31) * 32;
    int lrow = l & 15, hi = l >> 4;

    const __hip_bfloat16* w1t = w1t_all + (size_t)i * 512 * 64;
    const __hip_bfloat16* w2bt = w2bt_all + (size_t)i * 64 * 256;
    const float* b1w = wn_b1 + i * 256;
    const float* b1b = bn_b1 + i * 256;
    const float* b2b = bn_b2 + i * 64;
    __hip_bfloat16* h1out = h1_all + (size_t)i * NPER * 256;
    float* biasout = bias_all + (size_t)i * NPER * 64;

    {
        int chunk = w * 64 + l;
        int m = chunk >> 3, q = chunk & 7;
        int gq = q ^ (m & 7);
        GLOAD16((const char*)(summary + ((size_t)(m0 + m) << 6) + (gq << 3)),
                (char*)st + (size_t)(w * 64) * 16);
    }
    __syncthreads();

    f32x4 acc[8][2] = {};
    for (int ks = 0; ks < 2; ++ks) {
        short8v a[8], bb[2];
        for (int ii = 0; ii < 8; ++ii) {
            int n = w * 128 + ii * 16 + lrow;
            a[ii] = *(const short8v*)&w1t[(size_t)n * 64 + ks * 32 + hi * 8];
        }
        for (int j = 0; j < 2; ++j) {
            int m = j * 16 + lrow;
            int kk = ks * 4 + hi;
            bb[j] = *(const short8v*)((const char*)st + m * 128 + ((kk ^ (m & 7)) << 4));
        }
        for (int ii = 0; ii < 8; ++ii)
            for (int j = 0; j < 2; ++j)
                acc[ii][j] = __builtin_amdgcn_mfma_f32_16x16x32_bf16(a[ii], bb[j], acc[ii][j], 0, 0, 0);
    }
    if (w < 2) {
        for (int ii = 0; ii < 8; ++ii) {
            int n0_ = w * 128 + ii * 16 + hi * 4;
            float4 bw = *(const float4*)&b1w[n0_];
            float bwa[4] = {bw.x, bw.y, bw.z, bw.w};
            for (int j = 0; j < 2; ++j) {
                union { unsigned short s[4]; unsigned long long u; } pk;
                for (int r = 0; r < 4; ++r) {
                    float z = acc[ii][j][r] + bwa[r];
                    pk.s[r] = bf16u(z / (1.f + __expf(-z)));
                }
                int m = m0 + j * 16 + lrow;
                *(unsigned long long*)&h1out[(size_t)m * 256 + n0_] = pk.u;
            }
        }
    } else {
        for (int ii = 0; ii < 8; ++ii) {
            int nb0 = (w - 2) * 128 + ii * 16 + hi * 4;
            float4 bw = *(const float4*)&b1b[nb0];
            float bwa[4] = {bw.x, bw.y, bw.z, bw.w};
            for (int j = 0; j < 2; ++j) {
                union { unsigned short s[4]; unsigned long long u; } pk;
                for (int r = 0; r < 4; ++r) {
                    float z = acc[ii][j][r] + bwa[r];
                    pk.s[r] = bf16u(z / (1.f + __expf(-z)));
                }
                int mloc = j * 16 + lrow;
                int qq = nb0 >> 3;
                *(unsigned long long*)((char*)hb + mloc * 512 +
                                       ((qq ^ (mloc & 7)) << 4) + ((nb0 & 7) << 1)) = pk.u;
            }
        }
    }
    __syncthreads();

    f32x4 acc2[2] = {};
    for (int ks = 0; ks < 8; ++ks) {
        short8v a2 = *(const short8v*)&w2bt[(size_t)(w * 16 + lrow) * 256 + ks * 32 + hi * 8];
        for (int j = 0; j < 2; ++j) {
            int ml = j * 16 + lrow;
            int kk = ks * 4 + hi;
            short8v b2f = *(const short8v*)((const char*)hb + ml * 512 + ((kk ^ (ml & 7)) << 4));
            acc2[j] = __builtin_amdgcn_mfma_f32_16x16x32_bf16(a2, b2f, acc2[j], 0, 0, 0);
        }
    }
    {
        int c0 = w * 16 + hi * 4;
        float4 bv = *(const float4*)&b2b[c0];
        for (int j = 0; j < 2; ++j) {
            int m = m0 + j * 16 + lrow;
            float4 o;
            o.x = acc2[j][0] + bv.x; o.y = acc2[j][1] + bv.y;
            o.z = acc2[j][2] + bv.z; o.w = acc2[j][3] + bv.w;
            *(float4*)&biasout[(size_t)m * 64 + c0] = o;
        }
    }
}

// ---------------------------------------------------------------------------
// K4: wgt GEMM for BOTH hyper-blocks. M=1024, N=4096, K=256 each.
// 512 blocks: i = bid>>8; within: mt = bid&7, nt = (bid>>3)&31.
__global__ __launch_bounds__(256) void k_wgt_mfma(const __hip_bfloat16* __restrict__ h1_all,
                                                  const __hip_bfloat16* __restrict__ w2t_all,
                                                  const float* __restrict__ b2_all,
                                                  __hip_bfloat16* __restrict__ wgt_all) {
    __shared__ short sm[2][128 * 68];
    int t = threadIdx.x;
    int l = t & 63, w = t >> 6;
    int i = blockIdx.x >> 8;
    int bid8 = blockIdx.x & 255;
    int mt = bid8 & 7, nt = bid8 >> 3;
    int m0 = mt << 7, n0 = nt << 7;
    int wr = w >> 1, wc = w & 1;
    int lrow = l & 15, hi = l >> 4;

    const __hip_bfloat16* h1 = h1_all + (size_t)i * NPER * 256;
    const __hip_bfloat16* w2t = w2t_all + (size_t)i * 4096 * 256;
    const float* b2 = b2_all + (size_t)i * 4096;
    __hip_bfloat16* wgt = wgt_all + ((size_t)i << 22);

    f32x4 acc[4][4] = {};

    const char* gA = (const char*)(h1 + (size_t)m0 * 256);
    const char* gB = (const char*)(w2t + (size_t)n0 * 256);

    for (int ks = 0; ks < 4; ++ks) {
        int k0 = ks * 64;
        #pragma unroll
        for (int it = 0; it < 4; ++it) {
            int c = it * 256 + t;
            int row = c >> 3, q = c & 7;
            size_t goff = ((size_t)row * 256 + k0 + ((q ^ (row & 7)) << 3)) * 2;
            size_t ldst = (size_t)(it * 256 + w * 64) * 16;
            GLOAD16(gA + goff, (char*)sm[0] + ldst);
            GLOAD16(gB + goff, (char*)sm[1] + ldst);
        }
        __syncthreads();
        #pragma unroll
        for (int kk = 0; kk < 2; ++kk) {
            int kq = kk * 4 + hi;
            short8v a[4], b[4];
            #pragma unroll
            for (int fi = 0; fi < 4; ++fi) {
                int row = wc * 64 + fi * 16 + lrow;
                a[fi] = *(const short8v*)((const char*)sm[1] + row * 128 + ((kq ^ (row & 7)) << 4));
            }
            #pragma unroll
            for (int fj = 0; fj < 4; ++fj) {
                int row = wr * 64 + fj * 16 + lrow;
                b[fj] = *(const short8v*)((const char*)sm[0] + row * 128 + ((kq ^ (row & 7)) << 4));
            }
            #pragma unroll
            for (int fi = 0; fi < 4; ++fi)
                #pragma unroll
                for (int fj = 0; fj < 4; ++fj)
                    acc[fi][fj] = __builtin_amdgcn_mfma_f32_16x16x32_bf16(a[fi], b[fj], acc[fi][fj], 0, 0, 0);
        }
        __syncthreads();
    }

    short* epi = (short*)sm;
    #pragma unroll
    for (int fi = 0; fi < 4; ++fi) {
        int nl = wc * 64 + fi * 16 + hi * 4;
        float4 bv = *(const float4*)&b2[n0 + nl];
        float bva[4] = {bv.x, bv.y, bv.z, bv.w};
        #pragma unroll
        for (int fj = 0; fj < 4; ++fj) {
            int m = wr * 64 + fj * 16 + lrow;
            union { unsigned short s[4]; unsigned long long u; } pk;
            #pragma unroll
            for (int r = 0; r < 4; ++r)
                pk.s[r] = bf16u(acc[fi][fj][r] + bva[r]);
            *(unsigned long long*)((char*)epi + (size_t)m * 272 + nl * 2) = pk.u;
        }
    }
    __syncthreads();
    #pragma unroll
    for (int pass = 0; pass < 8; ++pass) {
        int row = pass * 16 + (t >> 4);
        int c8 = (t & 15) * 8;
        uint4 v = *(const uint4*)((const char*)epi + (size_t)row * 272 + c8 * 2);
        *(uint4*)&wgt[(size_t)(m0 + row) * 4096 + n0 + c8] = v;
    }
}

// ---------------------------------------------------------------------------
// K5: fused bmm for BOTH hyper-blocks. Per wave: one patch, tile lives in LDS.
// round r: nm = LN(prl); prl = wgt_r[n%1024] @ nm^T + bias_r + prl (bf16 in LDS).
__global__ __launch_bounds__(256) void k_bmm2(__hip_bfloat16* __restrict__ proc,
                                              const __hip_bfloat16* __restrict__ wgt_all,
                                              const float* __restrict__ bias_all,
                                              const float* __restrict__ ln_g,
                                              const float* __restrict__ ln_b) {
    __shared__ short prl[4][16][72];
    __shared__ short nm_lds[4][16][72];
    int t = threadIdx.x;
    int w = t >> 6, l = t & 63;
    int n = blockIdx.x * 4 + w;
    int nw = n & (NPER - 1);
    int p = l & 15, hi = l >> 4;

    // ---- stage proc tile (wave-private)
    {
        int pp = l >> 2, c16 = (l & 3) * 16;
        const __hip_bfloat16* srow = proc + ((size_t)n << 10) + (pp << 6) + c16;
        *(short8v*)&prl[w][pp][c16]     = *(const short8v*)srow;
        *(short8v*)&prl[w][pp][c16 + 8] = *(const short8v*)(srow + 8);
    }
    __syncthreads();

    for (int rnd = 0; rnd < 2; ++rnd) {
        const __hip_bfloat16* wrow = wgt_all + ((size_t)rnd << 22) + ((size_t)nw << 12);
        const float* brow = bias_all + ((size_t)rnd << 16) + ((size_t)nw << 6);

        // LN over channels of token p (4 lanes/token)
        short8v r0 = *(const short8v*)&prl[w][p][hi * 16];
        short8v r1 = *(const short8v*)&prl[w][p][hi * 16 + 8];
        float pr[16];
        #pragma unroll
        for (int e = 0; e < 8; ++e) { pr[e] = bf2f(r0[e]); pr[8 + e] = bf2f(r1[e]); }
        float s = 0.f, s2 = 0.f;
        #pragma unroll
        for (int e = 0; e < 16; ++e) { s += pr[e]; s2 += pr[e] * pr[e]; }
        s += __shfl_xor(s, 16);  s2 += __shfl_xor(s2, 16);
        s += __shfl_xor(s, 32);  s2 += __shfl_xor(s2, 32);
        float mean = s * (1.f / 64.f);
        float var = s2 * (1.f / 64.f) - mean * mean;
        float rinv = rsqrtf(var + 1e-5f);

        const float* gp = ln_g + rnd * 64 + (hi << 4);
        const float* bp = ln_b + rnd * 64 + (hi << 4);
        float gg[16], bb_[16];
        *(float4*)(gg)      = *(const float4*)(gp);
        *(float4*)(gg + 4)  = *(const float4*)(gp + 4);
        *(float4*)(gg + 8)  = *(const float4*)(gp + 8);
        *(float4*)(gg + 12) = *(const float4*)(gp + 12);
        *(float4*)(bb_)      = *(const float4*)(bp);
        *(float4*)(bb_ + 4)  = *(const float4*)(bp + 4);
        *(float4*)(bb_ + 8)  = *(const float4*)(bp + 8);
        *(float4*)(bb_ + 12) = *(const float4*)(bp + 12);

        short8v nm0, nm1;
        #pragma unroll
        for (int e = 0; e < 8; ++e)
            nm0[e] = bf16s((pr[e] - mean) * rinv * gg[e] + bb_[e]);
        #pragma unroll
        for (int e = 0; e < 8; ++e)
            nm1[e] = bf16s((pr[8 + e] - mean) * rinv * gg[8 + e] + bb_[8 + e]);
        *(short8v*)&nm_lds[w][p][hi * 16]     = nm0;
        *(short8v*)&nm_lds[w][p][hi * 16 + 8] = nm1;
        __syncthreads();

        // A-frags from global wgt (L2/L3-resident, 8KB/row)
        short8v af[4][2];
        #pragma unroll
        for (int ib = 0; ib < 4; ++ib)
            #pragma unroll
            for (int ks = 0; ks < 2; ++ks)
                af[ib][ks] = *(const short8v*)&wrow[(ib * 16 + p) * 64 + ks * 32 + hi * 8];

        short8v bf0 = *(const short8v*)&nm_lds[w][p][hi * 8];
        short8v bf1 = *(const short8v*)&nm_lds[w][p][32 + hi * 8];

        f32x4 acc[4] = {};
        #pragma unroll
        for (int ib = 0; ib < 4; ++ib) {
            acc[ib] = __builtin_amdgcn_mfma_f32_16x16x32_bf16(af[ib][0], bf0, acc[ib], 0, 0, 0);
            acc[ib] = __builtin_amdgcn_mfma_f32_16x16x32_bf16(af[ib][1], bf1, acc[ib], 0, 0, 0);
        }

        // update prl: (p, i = ib*16 + hi*4 + r), per-lane disjoint
        #pragma unroll
        for (int ib = 0; ib < 4; ++ib) {
            int i0 = ib * 16 + hi * 4;
            unsigned long long rr = *(const unsigned long long*)&prl[w][p][i0];
            float4 bsv = *(const float4*)&brow[i0];
            float ba[4] = {bsv.x, bsv.y, bsv.z, bsv.w};
            union { unsigned short s[4]; unsigned long long u; } stp;
            #pragma unroll
            for (int r = 0; r < 4; ++r) {
                float res = bf2f((short)((rr >> (16 * r)) & 0xffff));
                stp.s[r] = bf16u(acc[ib][r] + ba[r] + res);
            }
            *(unsigned long long*)&prl[w][p][i0] = stp.u;
        }
        __syncthreads();
    }

    // ---- store tile back (coalesced 16B chunks)
    #pragma unroll
    for (int pass = 0; pass < 2; ++pass) {
        int c = pass * 64 + l;
        int pp = c >> 3, c8 = (c & 7) * 8;
        uint4 v = *(const uint4*)&prl[w][pp][c8];
        *(uint4*)(proc + ((size_t)n << 10) + (pp << 6) + c8) = v;
    }
}

// ---------------------------------------------------------------------------
// K6: 1x1 conv (64->256) + pixel shuffle, MFMA; proc is bf16.
__global__ __launch_bounds__(256) void k_conv_mfma(const __hip_bfloat16* __restrict__ proc,
                                                   const __hip_bfloat16* __restrict__ cwt_g,
                                                   const float* __restrict__ cb,
                                                   float* __restrict__ out) {
    __shared__ short cwt[256 * 64];
    __shared__ short msb[128 * 64];
    __shared__ float cbl[256];
    int t = threadIdx.x;
    int l = t & 63, wv = t >> 6;
    int b = blockIdx.x >> 7, hh = blockIdx.x & 127;

    for (int it = 0; it < 8; ++it) {
        int cid0 = it * 256 + wv * 64;
        GLOAD16((const char*)cwt_g + ((size_t)(cid0 + l) << 4),
                (char*)cwt + ((size_t)cid0 << 4));
    }
    cbl[t] = cb[t];
    int ny = (hh >> 2) * 32, py = hh & 3;
    for (int it = 0; it < 4; ++it) {
        int chunk = it * 256 + wv * 64 + l;
        int w = chunk >> 3, q = chunk & 7;
        int n = (b << 10) + ny + (w >> 2);
        int p = (py << 2) + (w & 3);
        int gq = q ^ (w & 7);
        GLOAD16((const char*)proc + (((size_t)n << 10) + (p << 6) + (gq << 3)) * 2,
                (char*)msb + (size_t)(it * 256 + wv * 64) * 16);
    }
    __syncthreads();

    int wvo = wv >> 1, wvw = wv & 1;
    int lrow = l & 15, lhi = l >> 4;
    f32x4 acc[8][4] = {};
    for (int ks = 0; ks < 2; ++ks) {
        int q = ks * 4 + lhi;
        short8v a[8], bb[4];
        for (int i = 0; i < 8; ++i) {
            int ocr = wvo * 128 + i * 16 + lrow;
            a[i] = *(const short8v*)((const char*)cwt + ocr * 128 + ((q ^ (ocr & 7)) << 4));
        }
        for (int j = 0; j < 4; ++j) {
            int wr = wvw * 64 + j * 16 + lrow;
            bb[j] = *(const short8v*)((const char*)msb + wr * 128 + ((q ^ (wr & 7)) << 4));
        }
        for (int i = 0; i < 8; ++i)
            for (int j = 0; j < 4; ++j)
                acc[i][j] = __builtin_amdgcn_mfma_f32_16x16x32_bf16(a[i], bb[j], acc[i][j], 0, 0, 0);
    }

    for (int i = 0; i < 8; ++i) {
        int oc4 = wvo * 128 + i * 16 + lhi * 4;
        int c = oc4 >> 2;
        float cb0 = cbl[oc4], cb1 = cbl[oc4 + 1], cb2 = cbl[oc4 + 2], cb3 = cbl[oc4 + 3];
        float* row0 = out + (((size_t)b * 64 + c) * 256 + 2 * hh) * 256;
        float* row1 = row0 + 256;
        for (int j = 0; j < 4; ++j) {
            int w = wvw * 64 + j * 16 + lrow;
            ((float2*)row0)[w] = make_float2(acc[i][j][0] + cb0, acc[i][j][1] + cb1);
            ((float2*)row1)[w] = make_float2(acc[i][j][2] + cb2, acc[i][j][3] + cb3);
        }
    }
}

// ---------------------------------------------------------------------------
extern "C" void kernel_launch(void* const* d_in, const int* in_sizes, int n_in,
                              void* d_out, int out_size, void* d_ws, size_t ws_size,
                              hipStream_t stream) {
    const float* x      = (const float*)d_in[0];
    const float* pixpos = (const float*)d_in[1];
    const float* ppe_w1 = (const float*)d_in[2];
    const float* ppe_b1 = (const float*)d_in[3];
    const float* ppe_w2 = (const float*)d_in[4];
    const float* ppe_b2 = (const float*)d_in[5];
    const float* ln_g   = (const float*)d_in[6];
    const float* ln_b   = (const float*)d_in[7];
    const float* wn_w1  = (const float*)d_in[8];
    const float* wn_b1  = (const float*)d_in[9];
    const float* wn_w2  = (const float*)d_in[10];
    const float* wn_b2  = (const float*)d_in[11];
    const float* bn_w1  = (const float*)d_in[12];
    const float* bn_b1  = (const float*)d_in[13];
    const float* bn_w2  = (const float*)d_in[14];
    const float* bn_b2  = (const float*)d_in[15];
    const float* conv_w = (const float*)d_in[16];
    const float* conv_b = (const float*)d_in[17];
    float* out = (float*)d_out;

    char* wsb = (char*)d_ws;
    __hip_bfloat16* procb   = (__hip_bfloat16*)wsb; wsb += (size_t)NPAT * 1024 * 2;     // 16 MB
    __hip_bfloat16* wgt_all = (__hip_bfloat16*)wsb; wsb += (size_t)2 * NPER * 4096 * 2; // 16 MB
    __hip_bfloat16* h1      = (__hip_bfloat16*)wsb; wsb += (size_t)2 * NPER * 256 * 2;  //  1 MB
    __hip_bfloat16* w2t     = (__hip_bfloat16*)wsb; wsb += (size_t)2 * 4096 * 256 * 2;  //  4 MB
    float* bias             = (float*)wsb;          wsb += (size_t)2 * NPER * 64 * 4;   // 512 KB
    __hip_bfloat16* summ    = (__hip_bfloat16*)wsb; wsb += (size_t)NPER * 64 * 2;       // 128 KB
    __hip_bfloat16* w1t     = (__hip_bfloat16*)wsb; wsb += (size_t)2 * 512 * 64 * 2;    // 128 KB
    __hip_bfloat16* w2bt    = (__hip_bfloat16*)wsb; wsb += (size_t)2 * 64 * 256 * 2;    //  64 KB
    __hip_bfloat16* cwt_g   = (__hip_bfloat16*)wsb;                                     //  32 KB

    k_setup<<<2240, 256, 0, stream>>>(x, procb, pixpos, ppe_w1, ppe_b1, ppe_w2, ppe_b2,
                                      summ, wn_w2, conv_w, wn_w1, bn_w1, bn_w2,
                                      w2t, cwt_g, w1t, w2bt);
    k_mlp_mfma<<<64, 256, 0, stream>>>(summ, w1t, wn_b1, bn_b1, w2bt, bn_b2, h1, bias);
    k_wgt_mfma<<<512, 256, 0, stream>>>(h1, w2t, wn_b2, wgt_all);
    k_bmm2<<<2048, 256, 0, stream>>>(procb, wgt_all, bias, ln_g, ln_b);
    k_conv_mfma<<<1024, 256, 0, stream>>>(procb, cwt_g, conv_b, out);
}

// Round 10
// 83.029 us; speedup vs baseline: 2.9138x; 1.0780x over previous
//
#include <hip/hip_runtime.h>
#include <hip/hip_bf16.h>

// Problem constants
constexpr int NPAT = 8192;     // B*PH*PW = 8*32*32
constexpr int NPER = 1024;     // coords period: summary/h1/bias/wgt repeat every 1024

typedef __attribute__((ext_vector_type(8))) short short8v;   // 8 bf16
typedef __attribute__((ext_vector_type(4))) float f32x4;

#define GLOAD16(g, l) __builtin_amdgcn_global_load_lds( \
    (const __attribute__((address_space(1))) void*)(g), \
    (__attribute__((address_space(3))) void*)(l), 16, 0, 0)

__device__ inline short bf16s(float f) {
    __hip_bfloat16 h = __float2bfloat16(f);
    return *reinterpret_cast<short*>(&h);
}
__device__ inline unsigned short bf16u(float f) {
    __hip_bfloat16 h = __float2bfloat16(f);
    return *reinterpret_cast<unsigned short*>(&h);
}
__device__ inline float bf2f(short s) {
    return __uint_as_float(((unsigned int)(unsigned short)s) << 16);
}

// ---------------------------------------------------------------------------
// K-SETUP: block-range dispatch.
//   [0,1024):    unfold x -> proc bf16
//   [1024,1280): summary for 1024 distinct coords (4 patches/block)
//   [1280,2240): weight prep (w2t transpose, cwt swizzle, w1t/w2bt)
__global__ __launch_bounds__(256) void k_setup(const float* __restrict__ x,
                                               __hip_bfloat16* __restrict__ proc,
                                               const float* __restrict__ pixpos,
                                               const float* __restrict__ pw1,
                                               const float* __restrict__ pb1,
                                               const float* __restrict__ pw2,
                                               const float* __restrict__ pb2,
                                               __hip_bfloat16* __restrict__ summ,
                                               const float* __restrict__ w2,
                                               const float* __restrict__ cw,
                                               const float* __restrict__ wn_w1,
                                               const float* __restrict__ bn_w1,
                                               const float* __restrict__ bn_w2,
                                               __hip_bfloat16* __restrict__ w2t,
                                               __hip_bfloat16* __restrict__ cwt_g,
                                               __hip_bfloat16* __restrict__ w1t,
                                               __hip_bfloat16* __restrict__ w2bt) {
    __shared__ __align__(16) char smem[33024];
    int bid = blockIdx.x;
    int t = threadIdx.x;
    if (bid < 1024) {
        // ---- extract
        float (*tile)[129] = (float(*)[129])smem;
        int b = bid >> 7, h = bid & 127;
        for (int it = 0; it < 8; ++it) {
            int idx = it * 256 + t;
            int c = idx >> 5, w4 = (idx & 31) * 4;
            float4 v = *(const float4*)&x[(((size_t)b * 64 + c) * 128 + h) * 128 + w4];
            tile[c][w4] = v.x; tile[c][w4 + 1] = v.y;
            tile[c][w4 + 2] = v.z; tile[c][w4 + 3] = v.w;
        }
        __syncthreads();
        int ny = (h >> 2) * 32, py = h & 3;
        for (int it = 0; it < 16; ++it) {
            int pw = it * 8 + (t >> 5);
            int cc = (t & 31) * 2;
            int n = (b << 10) + ny + (pw >> 2);
            int p = (py << 2) + (pw & 3);
            unsigned int u = (unsigned int)bf16u(tile[cc][pw]) |
                             ((unsigned int)bf16u(tile[cc + 1][pw]) << 16);
            *(unsigned int*)(proc + ((size_t)n << 10) + (p << 6) + cc) = u;
        }
    } else if (bid < 1280) {
        // ---- summary: wave w handles distinct-coord patch n in [0,1024)
        float (*hs)[260] = (float(*)[260])smem;
        int l = t & 63, w = t >> 6;
        int n = (bid - 1024) * 4 + w;
        float cy = (float)(n >> 5) * (1.f / 31.f);
        float cx = (float)(n & 31) * (1.f / 31.f);
        for (int k4 = 0; k4 < 4; ++k4) {
            int k = k4 * 64 + l;
            float v = cy * pw1[k] + cx * pw1[256 + k] + pb1[k];
            hs[w][k] = v / (1.f + __expf(-v));
        }
        float acc = pb2[l];
        for (int k = 0; k < 256; ++k) acc += hs[w][k] * pw2[k * 64 + l];
        float pm = 0.f;
        for (int p = 0; p < 16; ++p) pm += pixpos[p * 64 + l];
        summ[(size_t)n * 64 + l] = __float2bfloat16(acc + pm * (1.f / 16.f));
    } else {
        int pb = bid - 1280;
        if (pb < 512) {
            float (*tile)[65] = (float(*)[65])smem;
            int b = pb >> 8;
            int rem = pb & 255;
            int kt = rem >> 6, nt = rem & 63;
            const float* src = w2 + (size_t)b * 256 * 4096 + (size_t)(kt * 64) * 4096 + nt * 64;
            for (int it = 0; it < 16; ++it) {
                int idx = t + it * 256;
                int r = idx >> 6, c = idx & 63;
                tile[r][c] = src[(size_t)r * 4096 + c];
            }
            __syncthreads();
            __hip_bfloat16* dst = w2t + (size_t)b * 4096 * 256 + (size_t)(nt * 64) * 256 + kt * 64;
            for (int it = 0; it < 16; ++it) {
                int idx = t + it * 256;
                int rr = idx >> 6, cc = idx & 63;
                dst[rr * 256 + cc] = __float2bfloat16(tile[cc][rr]);
            }
        } else if (pb < 576) {
            int idx = (pb - 512) * 256 + t;
            int oc = idx >> 6, cc = idx & 63;
            float v = cw[cc * 256 + oc];
            int el = oc * 64 + (((cc >> 3) ^ (oc & 7)) << 3) + (cc & 7);
            cwt_g[el] = __float2bfloat16(v);
        } else {
            int idx = (pb - 576) * 256 + t;
            if (idx < 2 * 512 * 64) {
                int b = idx >> 15; int r = idx & 32767; int n = r >> 6; int k = r & 63;
                const float* src = (n < 256) ? wn_w1 : bn_w1;
                float v = src[((size_t)b * 64 + k) * 256 + (n & 255)];
                w1t[idx] = __float2bfloat16(v);
            } else {
                int j = idx - 2 * 512 * 64;
                int b = j >> 14; int r = j & 16383; int c = r >> 8; int k = r & 255;
                float v = bn_w2[((size_t)b * 256 + k) * 64 + c];
                w2bt[j] = __float2bfloat16(v);
            }
        }
    }
}

// ---------------------------------------------------------------------------
// K3 (MFMA): both hyper-blocks, 1024 distinct patches. 64 blocks, 32 patches each.
__global__ __launch_bounds__(256) void k_mlp_mfma(const __hip_bfloat16* __restrict__ summary,
                                                  const __hip_bfloat16* __restrict__ w1t_all,
                                                  const float* __restrict__ wn_b1,
                                                  const float* __restrict__ bn_b1,
                                                  const __hip_bfloat16* __restrict__ w2bt_all,
                                                  const float* __restrict__ bn_b2,
                                                  __hip_bfloat16* __restrict__ h1_all,
                                                  float* __restrict__ bias_all) {
    __shared__ short st[32 * 64];
    __shared__ short hb[32 * 256];
    int t = threadIdx.x;
    int l = t & 63, w = t >> 6;
    int bi = blockIdx.x;
    int i = bi >> 5;
    int m0 = (bi & 31) * 32;
    int lrow = l & 15, hi = l >> 4;

    const __hip_bfloat16* w1t = w1t_all + (size_t)i * 512 * 64;
    const __hip_bfloat16* w2bt = w2bt_all + (size_t)i * 64 * 256;
    const float* b1w = wn_b1 + i * 256;
    const float* b1b = bn_b1 + i * 256;
    const float* b2b = bn_b2 + i * 64;
    __hip_bfloat16* h1out = h1_all + (size_t)i * NPER * 256;
    float* biasout = bias_all + (size_t)i * NPER * 64;

    {
        int chunk = w * 64 + l;
        int m = chunk >> 3, q = chunk & 7;
        int gq = q ^ (m & 7);
        GLOAD16((const char*)(summary + ((size_t)(m0 + m) << 6) + (gq << 3)),
                (char*)st + (size_t)(w * 64) * 16);
    }
    __syncthreads();

    f32x4 acc[8][2] = {};
    for (int ks = 0; ks < 2; ++ks) {
        short8v a[8], bb[2];
        for (int ii = 0; ii < 8; ++ii) {
            int n = w * 128 + ii * 16 + lrow;
            a[ii] = *(const short8v*)&w1t[(size_t)n * 64 + ks * 32 + hi * 8];
        }
        for (int j = 0; j < 2; ++j) {
            int m = j * 16 + lrow;
            int kk = ks * 4 + hi;
            bb[j] = *(const short8v*)((const char*)st + m * 128 + ((kk ^ (m & 7)) << 4));
        }
        for (int ii = 0; ii < 8; ++ii)
            for (int j = 0; j < 2; ++j)
                acc[ii][j] = __builtin_amdgcn_mfma_f32_16x16x32_bf16(a[ii], bb[j], acc[ii][j], 0, 0, 0);
    }
    if (w < 2) {
        for (int ii = 0; ii < 8; ++ii) {
            int n0_ = w * 128 + ii * 16 + hi * 4;
            float4 bw = *(const float4*)&b1w[n0_];
            float bwa[4] = {bw.x, bw.y, bw.z, bw.w};
            for (int j = 0; j < 2; ++j) {
                union { unsigned short s[4]; unsigned long long u; } pk;
                for (int r = 0; r < 4; ++r) {
                    float z = acc[ii][j][r] + bwa[r];
                    pk.s[r] = bf16u(z / (1.f + __expf(-z)));
                }
                int m = m0 + j * 16 + lrow;
                *(unsigned long long*)&h1out[(size_t)m * 256 + n0_] = pk.u;
            }
        }
    } else {
        for (int ii = 0; ii < 8; ++ii) {
            int nb0 = (w - 2) * 128 + ii * 16 + hi * 4;
            float4 bw = *(const float4*)&b1b[nb0];
            float bwa[4] = {bw.x, bw.y, bw.z, bw.w};
            for (int j = 0; j < 2; ++j) {
                union { unsigned short s[4]; unsigned long long u; } pk;
                for (int r = 0; r < 4; ++r) {
                    float z = acc[ii][j][r] + bwa[r];
                    pk.s[r] = bf16u(z / (1.f + __expf(-z)));
                }
                int mloc = j * 16 + lrow;
                int qq = nb0 >> 3;
                *(unsigned long long*)((char*)hb + mloc * 512 +
                                       ((qq ^ (mloc & 7)) << 4) + ((nb0 & 7) << 1)) = pk.u;
            }
        }
    }
    __syncthreads();

    f32x4 acc2[2] = {};
    for (int ks = 0; ks < 8; ++ks) {
        short8v a2 = *(const short8v*)&w2bt[(size_t)(w * 16 + lrow) * 256 + ks * 32 + hi * 8];
        for (int j = 0; j < 2; ++j) {
            int ml = j * 16 + lrow;
            int kk = ks * 4 + hi;
            short8v b2f = *(const short8v*)((const char*)hb + ml * 512 + ((kk ^ (ml & 7)) << 4));
            acc2[j] = __builtin_amdgcn_mfma_f32_16x16x32_bf16(a2, b2f, acc2[j], 0, 0, 0);
        }
    }
    {
        int c0 = w * 16 + hi * 4;
        float4 bv = *(const float4*)&b2b[c0];
        for (int j = 0; j < 2; ++j) {
            int m = m0 + j * 16 + lrow;
            float4 o;
            o.x = acc2[j][0] + bv.x; o.y = acc2[j][1] + bv.y;
            o.z = acc2[j][2] + bv.z; o.w = acc2[j][3] + bv.w;
            *(float4*)&biasout[(size_t)m * 64 + c0] = o;
        }
    }
}

// ---------------------------------------------------------------------------
// K4: wgt GEMM for BOTH hyper-blocks. M=1024, N=4096, K=256 each.
__global__ __launch_bounds__(256) void k_wgt_mfma(const __hip_bfloat16* __restrict__ h1_all,
                                                  const __hip_bfloat16* __restrict__ w2t_all,
                                                  const float* __restrict__ b2_all,
                                                  __hip_bfloat16* __restrict__ wgt_all) {
    __shared__ short sm[2][128 * 68];
    int t = threadIdx.x;
    int l = t & 63, w = t >> 6;
    int i = blockIdx.x >> 8;
    int bid8 = blockIdx.x & 255;
    int mt = bid8 & 7, nt = bid8 >> 3;
    int m0 = mt << 7, n0 = nt << 7;
    int wr = w >> 1, wc = w & 1;
    int lrow = l & 15, hi = l >> 4;

    const __hip_bfloat16* h1 = h1_all + (size_t)i * NPER * 256;
    const __hip_bfloat16* w2t = w2t_all + (size_t)i * 4096 * 256;
    const float* b2 = b2_all + (size_t)i * 4096;
    __hip_bfloat16* wgt = wgt_all + ((size_t)i << 22);

    f32x4 acc[4][4] = {};

    const char* gA = (const char*)(h1 + (size_t)m0 * 256);
    const char* gB = (const char*)(w2t + (size_t)n0 * 256);

    for (int ks = 0; ks < 4; ++ks) {
        int k0 = ks * 64;
        #pragma unroll
        for (int it = 0; it < 4; ++it) {
            int c = it * 256 + t;
            int row = c >> 3, q = c & 7;
            size_t goff = ((size_t)row * 256 + k0 + ((q ^ (row & 7)) << 3)) * 2;
            size_t ldst = (size_t)(it * 256 + w * 64) * 16;
            GLOAD16(gA + goff, (char*)sm[0] + ldst);
            GLOAD16(gB + goff, (char*)sm[1] + ldst);
        }
        __syncthreads();
        #pragma unroll
        for (int kk = 0; kk < 2; ++kk) {
            int kq = kk * 4 + hi;
            short8v a[4], b[4];
            #pragma unroll
            for (int fi = 0; fi < 4; ++fi) {
                int row = wc * 64 + fi * 16 + lrow;
                a[fi] = *(const short8v*)((const char*)sm[1] + row * 128 + ((kq ^ (row & 7)) << 4));
            }
            #pragma unroll
            for (int fj = 0; fj < 4; ++fj) {
                int row = wr * 64 + fj * 16 + lrow;
                b[fj] = *(const short8v*)((const char*)sm[0] + row * 128 + ((kq ^ (row & 7)) << 4));
            }
            #pragma unroll
            for (int fi = 0; fi < 4; ++fi)
                #pragma unroll
                for (int fj = 0; fj < 4; ++fj)
                    acc[fi][fj] = __builtin_amdgcn_mfma_f32_16x16x32_bf16(a[fi], b[fj], acc[fi][fj], 0, 0, 0);
        }
        __syncthreads();
    }

    short* epi = (short*)sm;
    #pragma unroll
    for (int fi = 0; fi < 4; ++fi) {
        int nl = wc * 64 + fi * 16 + hi * 4;
        float4 bv = *(const float4*)&b2[n0 + nl];
        float bva[4] = {bv.x, bv.y, bv.z, bv.w};
        #pragma unroll
        for (int fj = 0; fj < 4; ++fj) {
            int m = wr * 64 + fj * 16 + lrow;
            union { unsigned short s[4]; unsigned long long u; } pk;
            #pragma unroll
            for (int r = 0; r < 4; ++r)
                pk.s[r] = bf16u(acc[fi][fj][r] + bva[r]);
            *(unsigned long long*)((char*)epi + (size_t)m * 272 + nl * 2) = pk.u;
        }
    }
    __syncthreads();
    #pragma unroll
    for (int pass = 0; pass < 8; ++pass) {
        int row = pass * 16 + (t >> 4);
        int c8 = (t & 15) * 8;
        uint4 v = *(const uint4*)((const char*)epi + (size_t)row * 272 + c8 * 2);
        *(uint4*)&wgt[(size_t)(m0 + row) * 4096 + n0 + c8] = v;
    }
}

// ---------------------------------------------------------------------------
// K-STRIP: fused bmm(x2) + conv + pixel shuffle.
// Block = (b, gy, half): 16 patches (gx = half*16..+15), 512 threads (8 waves).
// LDS token tile tk[r=py*64+wl][cc 64] bf16, XOR-swizzled f(r) = (py + (wl&3) +
// 4*((wl>>2)&1)) & 7. bmm: LN in-register (lane owns the cc-set it feeds to
// MFMA B-frag), tokens updated in place. conv: wave (py = w>>1, oc-half = w&1).
__global__ __launch_bounds__(512) void k_strip(const __hip_bfloat16* __restrict__ proc,
                                               const __hip_bfloat16* __restrict__ wgt_all,
                                               const float* __restrict__ bias_all,
                                               const float* __restrict__ ln_g,
                                               const float* __restrict__ ln_b,
                                               const __hip_bfloat16* __restrict__ cwt_g,
                                               const float* __restrict__ cb,
                                               float* __restrict__ out) {
    __shared__ short tk[256 * 64];    // 32 KB
    __shared__ short cwt[256 * 64];   // 32 KB
    __shared__ float cbl[256];
    int t = threadIdx.x;
    int l = t & 63, w8 = t >> 6;
    int bid = blockIdx.x;
    int half = bid & 1, gy = (bid >> 1) & 31, b = bid >> 6;
    int nbase = (b << 10) + (gy << 5) + (half << 4);

    // ---- stage conv weights (2048 chunks)
    for (int it = 0; it < 4; ++it) {
        int cid0 = it * 512 + w8 * 64;
        GLOAD16((const char*)cwt_g + ((size_t)(cid0 + l) << 4),
                (char*)cwt + ((size_t)cid0 << 4));
    }
    if (t < 256) cbl[t] = cb[t];
    // ---- stage token tile (2048 chunks), pre-swizzled global source
    {
        const char* psrc = (const char*)(proc + ((size_t)nbase << 10));
        for (int it = 0; it < 4; ++it) {
            int c = it * 512 + t;
            int r = c >> 3, q = c & 7;
            int wl = r & 63, py = r >> 6;
            int f = (py + (wl & 3) + (((wl >> 2) & 1) << 2)) & 7;
            int goff = ((wl >> 2) << 11) + (((py << 2) + (wl & 3)) << 7) + ((q ^ f) << 4);
            GLOAD16(psrc + goff, (char*)tk + ((size_t)(it * 512 + w8 * 64) << 4));
        }
    }
    __syncthreads();

    // ---- bmm: wave handles patches gxl = w8*2, w8*2+1
    {
        int p = l & 15, hi = l >> 4;
        for (int rnd = 0; rnd < 2; ++rnd) {
            const float* gbase = ln_g + rnd * 64;
            const float* bbase = ln_b + rnd * 64;
            float4 g0 = *(const float4*)&gbase[hi * 8];
            float4 g1 = *(const float4*)&gbase[hi * 8 + 4];
            float4 g2 = *(const float4*)&gbase[32 + hi * 8];
            float4 g3 = *(const float4*)&gbase[32 + hi * 8 + 4];
            float4 e0 = *(const float4*)&bbase[hi * 8];
            float4 e1 = *(const float4*)&bbase[hi * 8 + 4];
            float4 e2 = *(const float4*)&bbase[32 + hi * 8];
            float4 e3 = *(const float4*)&bbase[32 + hi * 8 + 4];
            float gA[8] = {g0.x, g0.y, g0.z, g0.w, g1.x, g1.y, g1.z, g1.w};
            float gB[8] = {g2.x, g2.y, g2.z, g2.w, g3.x, g3.y, g3.z, g3.w};
            float eA[8] = {e0.x, e0.y, e0.z, e0.w, e1.x, e1.y, e1.z, e1.w};
            float eB[8] = {e2.x, e2.y, e2.z, e2.w, e3.x, e3.y, e3.z, e3.w};
            #pragma unroll
            for (int gg = 0; gg < 2; ++gg) {
                int gxl = (w8 << 1) + gg;
                int nw = (gy << 5) + (half << 4) + gxl;
                const __hip_bfloat16* wrow = wgt_all + ((size_t)rnd << 22) + ((size_t)nw << 12);
                const float* brow = bias_all + ((size_t)rnd << 16) + ((size_t)nw << 6);
                int wl = (gxl << 2) + (p & 3);
                int py = p >> 2;
                int r = (py << 6) + wl;
                int f = (py + (p & 3) + ((gxl & 1) << 2)) & 7;
                char* trow = (char*)tk + r * 128;
                // reads of pre-round state (sets A for LN, B for residual)
                short8v aA = *(const short8v*)(trow + ((hi ^ f) << 4));
                short8v aB = *(const short8v*)(trow + (((4 + hi) ^ f) << 4));
                unsigned long long res[4];
                #pragma unroll
                for (int ib = 0; ib < 4; ++ib) {
                    int i0 = (ib << 4) + (hi << 2);
                    res[ib] = *(const unsigned long long*)(trow + (((i0 >> 3) ^ f) << 4) + ((i0 & 7) << 1));
                }
                // LN stats (4 lanes per token hold disjoint cc sets)
                float va[8], vb[8];
                float s = 0.f, s2 = 0.f;
                #pragma unroll
                for (int e = 0; e < 8; ++e) {
                    va[e] = bf2f(aA[e]); vb[e] = bf2f(aB[e]);
                    s += va[e] + vb[e];
                    s2 += va[e] * va[e] + vb[e] * vb[e];
                }
                s += __shfl_xor(s, 16); s2 += __shfl_xor(s2, 16);
                s += __shfl_xor(s, 32); s2 += __shfl_xor(s2, 32);
                float mean = s * (1.f / 64.f);
                float var = s2 * (1.f / 64.f) - mean * mean;
                float rinv = rsqrtf(var + 1e-5f);
                short8v bf0, bf1;
                #pragma unroll
                for (int e = 0; e < 8; ++e) {
                    bf0[e] = bf16s((va[e] - mean) * rinv * gA[e] + eA[e]);
                    bf1[e] = bf16s((vb[e] - mean) * rinv * gB[e] + eB[e]);
                }
                // wgt A-fragments (L2-resident)
                short8v af[4][2];
                #pragma unroll
                for (int ib = 0; ib < 4; ++ib) {
                    af[ib][0] = *(const short8v*)&wrow[((ib * 16 + p) << 6) + hi * 8];
                    af[ib][1] = *(const short8v*)&wrow[((ib * 16 + p) << 6) + 32 + hi * 8];
                }
                f32x4 acc[4] = {};
                #pragma unroll
                for (int ib = 0; ib < 4; ++ib) {
                    acc[ib] = __builtin_amdgcn_mfma_f32_16x16x32_bf16(af[ib][0], bf0, acc[ib], 0, 0, 0);
                    acc[ib] = __builtin_amdgcn_mfma_f32_16x16x32_bf16(af[ib][1], bf1, acc[ib], 0, 0, 0);
                }
                // update tokens in place: out = D + bias + residual (bf16)
                #pragma unroll
                for (int ib = 0; ib < 4; ++ib) {
                    int i0 = (ib << 4) + (hi << 2);
                    float4 bsv = *(const float4*)&brow[i0];
                    float ba[4] = {bsv.x, bsv.y, bsv.z, bsv.w};
                    union { unsigned short s[4]; unsigned long long u; } pk;
                    #pragma unroll
                    for (int rr2 = 0; rr2 < 4; ++rr2) {
                        float rv = bf2f((short)((res[ib] >> (16 * rr2)) & 0xffff));
                        pk.s[rr2] = bf16u(acc[ib][rr2] + ba[rr2] + rv);
                    }
                    *(unsigned long long*)(trow + (((i0 >> 3) ^ f) << 4) + ((i0 & 7) << 1)) = pk.u;
                }
            }
            __syncthreads();
        }
    }

    // ---- conv: wave w8 -> (py = w8>>1, oc-half wvo = w8&1); 2 oc sub-passes
    {
        int py = w8 >> 1, wvo = w8 & 1;
        int lrow = l & 15, lhi = l >> 4;
        int hh = (gy << 2) + py;
        #pragma unroll
        for (int ih = 0; ih < 2; ++ih) {
            f32x4 acc[4][4] = {};
            #pragma unroll
            for (int ks = 0; ks < 2; ++ks) {
                int q = (ks << 2) + lhi;
                short8v a[4], bb[4];
                #pragma unroll
                for (int i = 0; i < 4; ++i) {
                    int ocr = wvo * 128 + (ih * 4 + i) * 16 + lrow;
                    a[i] = *(const short8v*)((const char*)cwt + ocr * 128 + ((q ^ (ocr & 7)) << 4));
                }
                #pragma unroll
                for (int j = 0; j < 4; ++j) {
                    int wl = (j << 4) + lrow;
                    int rr = (py << 6) + wl;
                    int ff = (py + (wl & 3) + (((wl >> 2) & 1) << 2)) & 7;
                    bb[j] = *(const short8v*)((const char*)tk + rr * 128 + ((q ^ ff) << 4));
                }
                #pragma unroll
                for (int i = 0; i < 4; ++i)
                    #pragma unroll
                    for (int j = 0; j < 4; ++j)
                        acc[i][j] = __builtin_amdgcn_mfma_f32_16x16x32_bf16(a[i], bb[j], acc[i][j], 0, 0, 0);
            }
            #pragma unroll
            for (int i = 0; i < 4; ++i) {
                int oc4 = wvo * 128 + (ih * 4 + i) * 16 + lhi * 4;
                int c = oc4 >> 2;
                float cb0 = cbl[oc4], cb1 = cbl[oc4 + 1];
                float cb2 = cbl[oc4 + 2], cb3 = cbl[oc4 + 3];
                float* row0 = out + (((size_t)b * 64 + c) * 256 + 2 * hh) * 256;
                float* row1 = row0 + 256;
                #pragma unroll
                for (int j = 0; j < 4; ++j) {
                    int ww = (half << 6) + (j << 4) + lrow;
                    ((float2*)row0)[ww] = make_float2(acc[i][j][0] + cb0, acc[i][j][1] + cb1);
                    ((float2*)row1)[ww] = make_float2(acc[i][j][2] + cb2, acc[i][j][3] + cb3);
                }
            }
        }
    }
}

// ---------------------------------------------------------------------------
extern "C" void kernel_launch(void* const* d_in, const int* in_sizes, int n_in,
                              void* d_out, int out_size, void* d_ws, size_t ws_size,
                              hipStream_t stream) {
    const float* x      = (const float*)d_in[0];
    const float* pixpos = (const float*)d_in[1];
    const float* ppe_w1 = (const float*)d_in[2];
    const float* ppe_b1 = (const float*)d_in[3];
    const float* ppe_w2 = (const float*)d_in[4];
    const float* ppe_b2 = (const float*)d_in[5];
    const float* ln_g   = (const float*)d_in[6];
    const float* ln_b   = (const float*)d_in[7];
    const float* wn_w1  = (const float*)d_in[8];
    const float* wn_b1  = (const float*)d_in[9];
    const float* wn_w2  = (const float*)d_in[10];
    const float* wn_b2  = (const float*)d_in[11];
    const float* bn_w1  = (const float*)d_in[12];
    const float* bn_b1  = (const float*)d_in[13];
    const float* bn_w2  = (const float*)d_in[14];
    const float* bn_b2  = (const float*)d_in[15];
    const float* conv_w = (const float*)d_in[16];
    const float* conv_b = (const float*)d_in[17];
    float* out = (float*)d_out;

    char* wsb = (char*)d_ws;
    __hip_bfloat16* procb   = (__hip_bfloat16*)wsb; wsb += (size_t)NPAT * 1024 * 2;     // 16 MB
    __hip_bfloat16* wgt_all = (__hip_bfloat16*)wsb; wsb += (size_t)2 * NPER * 4096 * 2; // 16 MB
    __hip_bfloat16* h1      = (__hip_bfloat16*)wsb; wsb += (size_t)2 * NPER * 256 * 2;  //  1 MB
    __hip_bfloat16* w2t     = (__hip_bfloat16*)wsb; wsb += (size_t)2 * 4096 * 256 * 2;  //  4 MB
    float* bias             = (float*)wsb;          wsb += (size_t)2 * NPER * 64 * 4;   // 512 KB
    __hip_bfloat16* summ    = (__hip_bfloat16*)wsb; wsb += (size_t)NPER * 64 * 2;       // 128 KB
    __hip_bfloat16* w1t     = (__hip_bfloat16*)wsb; wsb += (size_t)2 * 512 * 64 * 2;    // 128 KB
    __hip_bfloat16* w2bt    = (__hip_bfloat16*)wsb; wsb += (size_t)2 * 64 * 256 * 2;    //  64 KB
    __hip_bfloat16* cwt_g   = (__hip_bfloat16*)wsb;                                     //  32 KB

    k_setup<<<2240, 256, 0, stream>>>(x, procb, pixpos, ppe_w1, ppe_b1, ppe_w2, ppe_b2,
                                      summ, wn_w2, conv_w, wn_w1, bn_w1, bn_w2,
                                      w2t, cwt_g, w1t, w2bt);
    k_mlp_mfma<<<64, 256, 0, stream>>>(summ, w1t, wn_b1, bn_b1, w2bt, bn_b2, h1, bias);
    k_wgt_mfma<<<512, 256, 0, stream>>>(h1, w2t, wn_b2, wgt_all);
    k_strip<<<512, 512, 0, stream>>>(procb, wgt_all, bias, ln_g, ln_b,
                                     cwt_g, conv_b, out);
}